// Round 7
// baseline (723.491 us; speedup 1.0000x reference)
//
#include <hip/hip_runtime.h>
#include <math.h>

#define N_NODES 50000
#define N_EDGES 500000

// ---------- f16 pair helpers ----------
typedef _Float16 h2_t __attribute__((ext_vector_type(2)));
__device__ inline float pk(float a, float b) {
    h2_t h; h[0] = (_Float16)a; h[1] = (_Float16)b;
    float r; __builtin_memcpy(&r, &h, 4); return r;
}
__device__ inline float2 upk(float p) {
    h2_t h; __builtin_memcpy(&h, &p, 4);
    return make_float2((float)h[0], (float)h[1]);
}
__device__ inline float dot2f(float pa, float pb, float c) {
    h2_t ha, hb; __builtin_memcpy(&ha, &pa, 4); __builtin_memcpy(&hb, &pb, 4);
    return __builtin_amdgcn_fdot2(ha, hb, c, false);
}

// ---------- MFMA types ----------
typedef _Float16 f16x8 __attribute__((ext_vector_type(8)));
typedef float f32x4 __attribute__((ext_vector_type(4)));

// =================== dual-CSR build (dst-sorted eid + src-sorted eid_src) ==============
__global__ void k_deg_count(const int* __restrict__ eidx,
                            int* __restrict__ degi, int* __restrict__ degs) {
    int i = blockIdx.x * blockDim.x + threadIdx.x;
    if (i < N_EDGES) {
        atomicAdd(degi + eidx[N_EDGES + i], 1);  // dst
        atomicAdd(degs + eidx[i], 1);            // src
    }
}

__global__ void k_block_sums2(const int* __restrict__ degi, const int* __restrict__ degs,
                              int* __restrict__ partials, int n) {
    const int* deg = blockIdx.y ? degs : degi;
    int* part = partials + blockIdx.y * 256;
    __shared__ int sm[256];
    int i = blockIdx.x * 256 + threadIdx.x;
    sm[threadIdx.x] = (i < n) ? deg[i] : 0;
    __syncthreads();
    for (int s = 128; s > 0; s >>= 1) {
        if (threadIdx.x < s) sm[threadIdx.x] += sm[threadIdx.x + s];
        __syncthreads();
    }
    if (threadIdx.x == 0) part[blockIdx.x] = sm[0];
}

// two blocks: each scans its own 256-entry partials array (exclusive)
__global__ void k_scan_partials2(int* partials, int nb) {
    int* part = partials + blockIdx.x * 256;
    __shared__ int sm[256];
    int v = (threadIdx.x < nb) ? part[threadIdx.x] : 0;
    sm[threadIdx.x] = v;
    __syncthreads();
    for (int off = 1; off < 256; off <<= 1) {
        int t = (threadIdx.x >= off) ? sm[threadIdx.x - off] : 0;
        __syncthreads();
        sm[threadIdx.x] += t;
        __syncthreads();
    }
    if (threadIdx.x < nb) part[threadIdx.x] = sm[threadIdx.x] - v;
}

// also writes the cursor copies
__global__ void k_scan_final2(const int* __restrict__ degi, const int* __restrict__ degs,
                              const int* __restrict__ partials,
                              int* __restrict__ row_d, int* __restrict__ row_s,
                              int* __restrict__ cur_d, int* __restrict__ cur_s, int n) {
    const int* deg = blockIdx.y ? degs : degi;
    const int* part = partials + blockIdx.y * 256;
    int* row = blockIdx.y ? row_s : row_d;
    int* cur = blockIdx.y ? cur_s : cur_d;
    __shared__ int sm[256];
    int i = blockIdx.x * 256 + threadIdx.x;
    int v = (i < n) ? deg[i] : 0;
    sm[threadIdx.x] = v;
    __syncthreads();
    for (int off = 1; off < 256; off <<= 1) {
        int t = (threadIdx.x >= off) ? sm[threadIdx.x - off] : 0;
        __syncthreads();
        sm[threadIdx.x] += t;
        __syncthreads();
    }
    if (i < n) {
        int rv = part[blockIdx.x] + sm[threadIdx.x] - v;
        row[i] = rv; cur[i] = rv;
    }
    if (i == n - 1) row[n] = part[blockIdx.x] + sm[threadIdx.x];
}

__global__ void k_fill_slots(const int* __restrict__ eidx,
                             int* __restrict__ cur_d, int* __restrict__ cur_s,
                             int* __restrict__ eid, int* __restrict__ eid_src) {
    int i = blockIdx.x * blockDim.x + threadIdx.x;
    if (i < N_EDGES) {
        int pd = atomicAdd(cur_d + eidx[N_EDGES + i], 1);
        eid[pd] = i;
        int ps = atomicAdd(cur_s + eidx[i], 1);
        eid_src[ps] = i;
    }
}

// ---------------- weight prep: Ct pack, nc_w1 transpose, + LDS-ready f16 images --------
// New: prepacks the transposed f16-pair weight images in their exact LDS layouts so
// per-block staging becomes a conflict-free linear float4 copy (the in-kernel repack
// had word-stride-36/68 LDS writes = 8-way bank conflicts, 12.4M/dispatch at R6).
// Layouts (words): W12tp = W1t[128 c][36] ++ W2t[64 c][68]  (8960 words)
//                  Wm*tp = Wt[128 c][36]                    (4608 words each)
__global__ void k_prep_weights(const float* __restrict__ C /*[64 k][64 j]*/, float* __restrict__ Ctp,
                               const float* __restrict__ nc_w1 /*[72][64]*/, float* __restrict__ ncw1t,
                               const float* __restrict__ ee_w1 /*[38][128]*/,
                               const float* __restrict__ ee_w2 /*[128][64]*/,
                               float* __restrict__ W12tp,
                               const float* __restrict__ m1w /*[64][128]*/, float* __restrict__ Wm1tp,
                               const float* __restrict__ m2w /*[64][128]*/, float* __restrict__ Wm2tp) {
    int i = blockIdx.x * 256 + threadIdx.x;
    if (i < 2048) {
        int j = i >> 5, k2 = i & 31;
        Ctp[i] = pk(C[(2 * k2) * 64 + j], C[(2 * k2 + 1) * 64 + j]);
        return;
    }
    int t = i - 2048;
    if (t < 72 * 64) {
        int k = t / 64, j = t - k * 64;
        ncw1t[j * 72 + k] = nc_w1[k * 64 + j];
        return;
    }
    int u = t - 72 * 64;
    if (u < 4608) {                        // W1t
        int c = u / 36, w = u % 36;
        float v = 0.f;
        if (w < 32) {
            float a = (2 * w < 38) ? ee_w1[(2 * w) * 128 + c] : 0.f;
            float b = (2 * w + 1 < 38) ? ee_w1[(2 * w + 1) * 128 + c] : 0.f;
            v = pk(a, b);
        }
        W12tp[u] = v;
        return;
    }
    u -= 4608;
    if (u < 4352) {                        // W2t
        int c = u / 68, w = u % 68;
        float v = 0.f;
        if (w < 64) v = pk(ee_w2[(2 * w) * 64 + c], ee_w2[(2 * w + 1) * 64 + c]);
        W12tp[4608 + u] = v;
        return;
    }
    u -= 4352;
    if (u < 4608) {                        // Wm1t
        int c = u / 36, w = u % 36;
        float v = 0.f;
        if (w < 32) v = pk(m1w[(2 * w) * 128 + c], m1w[(2 * w + 1) * 128 + c]);
        Wm1tp[u] = v;
        return;
    }
    u -= 4608;
    if (u < 4608) {                        // Wm2t
        int c = u / 36, w = u % 36;
        float v = 0.f;
        if (w < 32) v = pk(m2w[(2 * w) * 128 + c], m2w[(2 * w + 1) * 128 + c]);
        Wm2tp[u] = v;
    }
}

// ---------------- edge encoder, MFMA + persistent weights + 4 tiles/block --------------
// LDS (halfwords): W1t [128][72] @0, W2t [64][136] @9216 (persistent across tiles),
// tile region @17920 (8704 hw): F [64][72] -> H [64][136] -> O [64][72] overlay.
// Weights staged ONCE per block via linear float4 copy (conflict-free, coalesced).
#define EE_TILES 4
#define EE_W1O 0
#define EE_W2O 9216
#define EE_TO 17920
#define EE_SMH2 26624

__global__ __launch_bounds__(256) void k_edge_enc_mfma(
    const float* __restrict__ la, const float* __restrict__ tse,
    const int* __restrict__ bp, const int* __restrict__ tt,
    const float* __restrict__ cr, const float* __restrict__ tsp,
    const float* __restrict__ tg, const float* __restrict__ r7,
    const float* __restrict__ r30,
    const float* __restrict__ tx_emb, const float* __restrict__ bank_emb,
    const float* __restrict__ W12tp, const float* __restrict__ eb1,
    const float* __restrict__ eb2,
    float* __restrict__ eap_g /*E x 32 packed*/, int n_edges) {
    __shared__ __align__(16) _Float16 sm[EE_SMH2];
    float* smf = (float*)sm;  // word view
    int tid = threadIdx.x;

    // ---- stage W1t+W2t once: 2240 float4s, linear ----
    {
        const float4* Wg = (const float4*)W12tp;
        float4* Wl = (float4*)sm;
#pragma unroll
        for (int i = 0; i < 9; i++) {
            int idx = tid + 256 * i;
            if (idx < 2240) Wl[idx] = Wg[idx];
        }
    }

    int lane = tid & 63;
    int wv = tid >> 6;
    int lrow = lane & 15;
    int lk = (lane >> 4) << 3;
    int rbase = (lane >> 4) << 2;

#pragma unroll 1
    for (int tile = 0; tile < EE_TILES; tile++) {
        int t0 = (blockIdx.x * EE_TILES + tile) * 64;
        if (t0 >= n_edges) break;
        __syncthreads();  // weights staged (tile 0) / prev O copy-out done (tile>0)

        // ---- feature build into F @ word 8960, stride 36 words ----
        {
            int el = tid & 63, g = tid >> 6;
            int e = t0 + el;
            bool ok = e < n_edges;
            float* Fr = smf + 8960 + el * 36;
            if (g == 0) {
                Fr[0] = ok ? pk(la[e], cr[e]) : 0.f;
                Fr[1] = ok ? pk(tsp[e], tg[e]) : 0.f;
                Fr[2] = ok ? pk(r7[e], r30[e]) : 0.f;
#pragma unroll
                for (int z = 19; z < 32; z++) Fr[z] = 0.f;  // K pad -> zero
            } else if (g == 1) {
                float4 a = make_float4(0, 0, 0, 0), b = a;
                if (ok) { a = ((const float4*)(tse + (long)e * 8))[0];
                          b = ((const float4*)(tse + (long)e * 8))[1]; }
                Fr[3] = pk(a.x, a.y); Fr[4] = pk(a.z, a.w);
                Fr[5] = pk(b.x, b.y); Fr[6] = pk(b.z, b.w);
            } else if (g == 2) {
                float4 a = make_float4(0, 0, 0, 0), b = a;
                if (ok) { int txi = tt[e];
                          a = ((const float4*)(tx_emb + (long)txi * 8))[0];
                          b = ((const float4*)(tx_emb + (long)txi * 8))[1]; }
                Fr[7] = pk(a.x, a.y); Fr[8] = pk(a.z, a.w);
                Fr[9] = pk(b.x, b.y); Fr[10] = pk(b.z, b.w);
            } else {
                float4 a = make_float4(0, 0, 0, 0), b = a, c = a, d = a;
                if (ok) {
                    int bk0 = bp[e * 2 + 0], bk1 = bp[e * 2 + 1];
                    a = ((const float4*)(bank_emb + (long)bk0 * 8))[0];
                    b = ((const float4*)(bank_emb + (long)bk0 * 8))[1];
                    c = ((const float4*)(bank_emb + (long)bk1 * 8))[0];
                    d = ((const float4*)(bank_emb + (long)bk1 * 8))[1];
                }
                Fr[11] = pk(a.x, a.y); Fr[12] = pk(a.z, a.w);
                Fr[13] = pk(b.x, b.y); Fr[14] = pk(b.z, b.w);
                Fr[15] = pk(c.x, c.y); Fr[16] = pk(c.z, c.w);
                Fr[17] = pk(d.x, d.y); Fr[18] = pk(d.z, d.w);
            }
        }
        __syncthreads();

        // ---- GEMM1 ----
        f16x8 a0 = *(const f16x8*)(sm + EE_TO + (wv * 16 + lrow) * 72 + lk);
        f16x8 a1 = *(const f16x8*)(sm + EE_TO + (wv * 16 + lrow) * 72 + 32 + lk);
        f32x4 acc[8];
#pragma unroll
        for (int ct = 0; ct < 8; ct++) {
            const _Float16* wb = sm + EE_W1O + (ct * 16 + lrow) * 72 + lk;
            f16x8 b0 = *(const f16x8*)(wb);
            f16x8 b1 = *(const f16x8*)(wb + 32);
            f32x4 z = {0.f, 0.f, 0.f, 0.f};
            acc[ct] = __builtin_amdgcn_mfma_f32_16x16x32_f16(a0, b0, z, 0, 0, 0);
            acc[ct] = __builtin_amdgcn_mfma_f32_16x16x32_f16(a1, b1, acc[ct], 0, 0, 0);
        }
        __syncthreads();  // F fully consumed -> overlay with H

        // ---- bias + relu -> H (f16, stride 136 hw) ----
#pragma unroll
        for (int ct = 0; ct < 8; ct++) {
            int col = ct * 16 + lrow;
            float bias = eb1[col];
#pragma unroll
            for (int r = 0; r < 4; r++) {
                int row = wv * 16 + rbase + r;
                sm[EE_TO + row * 136 + col] = (_Float16)fmaxf(acc[ct][r] + bias, 0.f);
            }
        }
        __syncthreads();

        // ---- GEMM2 ----
        f32x4 acc2[4];
#pragma unroll
        for (int ct = 0; ct < 4; ct++) { f32x4 z = {0.f, 0.f, 0.f, 0.f}; acc2[ct] = z; }
#pragma unroll
        for (int ks = 0; ks < 4; ks++) {
            f16x8 av = *(const f16x8*)(sm + EE_TO + (wv * 16 + lrow) * 136 + ks * 32 + lk);
#pragma unroll
            for (int ct = 0; ct < 4; ct++) {
                f16x8 bv = *(const f16x8*)(sm + EE_W2O + (ct * 16 + lrow) * 136 + ks * 32 + lk);
                acc2[ct] = __builtin_amdgcn_mfma_f32_16x16x32_f16(av, bv, acc2[ct], 0, 0, 0);
            }
        }
        __syncthreads();  // H fully consumed -> overlay with O

        // ---- bias -> O (f16, stride 72 hw, natural pair order == eap_g layout) ----
#pragma unroll
        for (int ct = 0; ct < 4; ct++) {
            int col = ct * 16 + lrow;
            float bias = eb2[col];
#pragma unroll
            for (int r = 0; r < 4; r++) {
                int row = wv * 16 + rbase + r;
                sm[EE_TO + row * 72 + col] = (_Float16)(acc2[ct][r] + bias);
            }
        }
        __syncthreads();

        // ---- coalesced copy-out: 64 edges x 32 u32 ----
#pragma unroll
        for (int rep = 0; rep < 2; rep++) {
            int idx = rep * 256 + tid;     // 0..511
            int el = idx >> 3, c4 = idx & 7;
            int e = t0 + el;
            if (e < n_edges) {
                float4 v = *(const float4*)(sm + EE_TO + el * 72 + c4 * 8);
                *((float4*)(eap_g + (long)e * 32 + c4 * 4)) = v;
            }
        }
    }
}

// ---------------- node-level GEMM via MFMA (verified R6) -------------------------------
template <int K1, int K2, int JC, bool RELU, bool DIV2, bool PACKOUT>
__global__ __launch_bounds__(256) void k_node_gemm_mfma(
    const float* __restrict__ in1, int ld1,
    const float* __restrict__ in2, int ld2,
    const int* __restrict__ degv,
    const float* __restrict__ W, int ldw,
    const float* __restrict__ bias,
    float* __restrict__ out, int ldo, int nrows) {
    constexpr int NC = (K1 + K2) / 64;
    constexpr int NCT = JC / 16;
    constexpr int AB_HW = 4608 + JC * 72;
    constexpr int OUT_HW = PACKOUT ? 64 * (JC + 8) : 64 * (JC + 4) * 2;
    constexpr int SM_HW = AB_HW > OUT_HW ? AB_HW : OUT_HW;
    __shared__ __align__(16) _Float16 sm[SM_HW];
    float* smw = (float*)sm;  // u32 word view
    int tid = threadIdx.x;
    int t0 = blockIdx.x * 64;

    int lane = tid & 63, wv = tid >> 6;
    int lrow = lane & 15, lk = (lane >> 4) << 3, rbase = (lane >> 4) << 2;

    f32x4 acc[NCT];
#pragma unroll
    for (int ct = 0; ct < NCT; ct++) {
        float b = bias ? bias[ct * 16 + lrow] : 0.f;
        f32x4 v = {b, b, b, b};
        acc[ct] = v;
    }

#pragma unroll 1
    for (int kc = 0; kc < NC; kc++) {
        __syncthreads();
        // ---- stage A chunk (coalesced float4, f16 into [64][72]) ----
        {
            const float* src = (kc * 64 < K1) ? in1 : in2;
            int ld = (kc * 64 < K1) ? ld1 : ld2;
            int ko = (kc * 64 < K1) ? kc * 64 : kc * 64 - K1;
            bool isdiv = DIV2 && (kc * 64 >= K1);
#pragma unroll
            for (int i = 0; i < 4; i++) {
                int f = tid + 256 * i;         // float4 id 0..1023
                int row = f >> 4, c4 = f & 15;
                int grow = t0 + row;
                float4 v = make_float4(0, 0, 0, 0);
                if (grow < nrows) {
                    v = *(const float4*)(src + (long)grow * ld + ko + c4 * 4);
                    if (isdiv) {
                        float dv = 1.f / ((float)degv[grow] + 1e-6f);
                        v.x *= dv; v.y *= dv; v.z *= dv; v.w *= dv;
                    }
                }
                float2 o; o.x = pk(v.x, v.y); o.y = pk(v.z, v.w);
                *((float2*)(sm + row * 72 + c4 * 4)) = o;
            }
        }
        // ---- stage W chunk: Wt[c][kp] = {W[kb+2kp][c], W[kb+2kp+1][c]} ----
        {
            int kb = kc * 64;
            constexpr int NW = JC * 32 / 256;
#pragma unroll
            for (int i = 0; i < NW; i++) {
                int idx = tid + 256 * i;
                int kp = idx / JC, c = idx % JC;
                smw[2304 + c * 36 + kp] = pk(W[(long)(kb + 2 * kp) * ldw + c],
                                             W[(long)(kb + 2 * kp + 1) * ldw + c]);
            }
        }
        __syncthreads();
        // ---- MFMA: 2 k-steps x NCT col-tiles ----
        f16x8 a0 = *(const f16x8*)(sm + (wv * 16 + lrow) * 72 + lk);
        f16x8 a1 = *(const f16x8*)(sm + (wv * 16 + lrow) * 72 + 32 + lk);
#pragma unroll
        for (int ct = 0; ct < NCT; ct++) {
            const _Float16* wb = sm + 4608 + (ct * 16 + lrow) * 72 + lk;
            f16x8 b0 = *(const f16x8*)(wb);
            f16x8 b1 = *(const f16x8*)(wb + 32);
            acc[ct] = __builtin_amdgcn_mfma_f32_16x16x32_f16(a0, b0, acc[ct], 0, 0, 0);
            acc[ct] = __builtin_amdgcn_mfma_f32_16x16x32_f16(a1, b1, acc[ct], 0, 0, 0);
        }
    }
    __syncthreads();

    if constexpr (PACKOUT) {
#pragma unroll
        for (int ct = 0; ct < NCT; ct++) {
            int col = ct * 16 + lrow;
#pragma unroll
            for (int r = 0; r < 4; r++) {
                float v = acc[ct][r];
                if (RELU) v = fmaxf(v, 0.f);
                sm[(wv * 16 + rbase + r) * (JC + 8) + col] = (_Float16)v;
            }
        }
        __syncthreads();
        constexpr int F4R = JC / 8;
        constexpr int NO = 64 * F4R / 256;
#pragma unroll
        for (int i = 0; i < NO; i++) {
            int idx = tid + 256 * i;
            int row = idx / F4R, c4 = idx % F4R;
            int grow = t0 + row;
            if (grow < nrows) {
                float4 v = *(const float4*)(sm + row * (JC + 8) + c4 * 8);
                *((float4*)(out + (long)grow * ldo + c4 * 4)) = v;
            }
        }
    } else {
        float* Of = smw;  // f32 [64][JC+4]
#pragma unroll
        for (int ct = 0; ct < NCT; ct++) {
            int col = ct * 16 + lrow;
#pragma unroll
            for (int r = 0; r < 4; r++) {
                float v = acc[ct][r];
                if (RELU) v = fmaxf(v, 0.f);
                Of[(wv * 16 + rbase + r) * (JC + 4) + col] = v;
            }
        }
        __syncthreads();
        constexpr int F4R = JC / 4;
        constexpr int NO = 64 * F4R / 256;
#pragma unroll
        for (int i = 0; i < NO; i++) {
            int idx = tid + 256 * i;
            int row = idx / F4R, c4 = idx % F4R;
            int grow = t0 + row;
            if (grow < nrows) {
                float4 v = *(const float4*)(Of + row * (JC + 4) + c4 * 4);
                *((float4*)(out + (long)grow * ldo + c4 * 4)) = v;
            }
        }
    }
}

// ---------------- edge-cls prep: nSp/nDp, j-split (R4-proven config) -------------------
__global__ __launch_bounds__(256) void k_ec_prep(
    const float* __restrict__ ne, const float* __restrict__ ec_w1,
    float* __restrict__ nSp, float* __restrict__ nDp) {
    int n = blockIdx.x * blockDim.x + threadIdx.x;
    if (n >= N_NODES) return;
    int half = blockIdx.y >> 1;
    int j0 = (blockIdx.y & 1) * 32;
    const float* W = ec_w1 + (half ? 64 * 64 : 0);
    float* outp = half ? nDp : nSp;
    float acc[32];
#pragma unroll
    for (int j = 0; j < 32; j++) acc[j] = 0.f;
    const float* r = ne + (long)n * 64;
#pragma unroll 1
    for (int kq = 0; kq < 16; kq++) {
        float4 xv = *(const float4*)(r + kq * 4);
        const float* xf = (const float*)&xv;
#pragma unroll
        for (int kk = 0; kk < 4; kk++) {
            const float* wr = W + (kq * 4 + kk) * 64 + j0;
#pragma unroll
            for (int j = 0; j < 32; j++) acc[j] = fmaf(xf[kk], wr[j], acc[j]);
        }
    }
    float* orow = outp + (long)n * 32 + (j0 >> 1);
#pragma unroll
    for (int j2 = 0; j2 < 16; j2++) orow[j2] = pk(acc[2 * j2], acc[2 * j2 + 1]);
}

// ---------------- msg GEMM via MFMA (swapped operands) + segmented sum -----------------
// Wt now prepacked in global (Wt_g, [128 c][36 words]) -> linear conflict-free staging.
__global__ __launch_bounds__(256) void k_msg_seg_mfma(
    const float* __restrict__ Pp /*N x 64 packed*/, const float* __restrict__ eap_g,
    const float* __restrict__ Wt_g /*4608 words*/, const float* __restrict__ bias,
    const int* __restrict__ src, const int* __restrict__ dst,
    const int* __restrict__ eid,
    float* __restrict__ s, int n_edges) {
    __shared__ __align__(16) float smem[8320];   // 33280 B (Mt f32[128][65])
    _Float16* smh = (_Float16*)smem;
    float* Mt = smem;
    __shared__ int sn_s[64];
    __shared__ int es_s[64];
    __shared__ int nid_s[64];
    __shared__ int bound_s[2];
    int tid = threadIdx.x;
    int t0 = blockIdx.x * 64;

    if (tid < 64) {
        int slot = t0 + tid;
        int e = (slot < n_edges) ? eid[slot] : 0;
        es_s[tid] = e;
        sn_s[tid] = src[e];
        nid_s[tid] = (slot < n_edges) ? dst[e] : -1;
    }
    if (tid == 64) bound_s[0] = (t0 > 0) ? dst[eid[t0 - 1]] : -1;
    if (tid == 65) bound_s[1] = (t0 + 64 < n_edges) ? dst[eid[t0 + 64]] : -1;

    // ---- stage W^T: linear float4 copy (conflict-free, coalesced) ----
    {
        const float4* Wg = (const float4*)Wt_g;
        float4* Wl = (float4*)smem;
#pragma unroll
        for (int i = 0; i < 5; i++) {
            int idx = tid + 256 * i;
            if (idx < 1152) Wl[idx] = Wg[idx];
        }
    }
    __syncthreads();

    int lane = tid & 63;
    int wv = tid >> 6;
    int lrow = lane & 15;
    int lk = (lane >> 4) << 3;
    int rbase = (lane >> 4) << 2;

    // ---- early P gathers + bias (consumed after MFMA) ----
    int srcs[4];
#pragma unroll
    for (int ct = 0; ct < 4; ct++) srcs[ct] = sn_s[ct * 16 + lrow];
    float2 pvr[2][4];
    float4 bv4[2];
#pragma unroll
    for (int rt = 0; rt < 2; rt++) {
        int chb = wv * 32 + rt * 16 + rbase;
        bv4[rt] = *(const float4*)(bias + chb);
#pragma unroll
        for (int ct = 0; ct < 4; ct++)
            pvr[rt][ct] = *(const float2*)(Pp + (long)srcs[ct] * 64 + (chb >> 1));
    }

    // ---- stage ea rows (B operand) ----
#pragma unroll
    for (int i = 0; i < 2; i++) {
        int idx = tid + 256 * i;        // 0..511
        int el = idx >> 3, c = idx & 7;
        float4 v = ((const float4*)(eap_g + (long)es_s[el] * 32))[c];
        *((float4*)(smh + 9216 + el * 72 + c * 8)) = v;
    }
    __syncthreads();

    // ---- MFMA: wave wv owns channels wv*32..+31 (2 row-tiles) x 4 edge col-tiles ----
    f32x4 acc[2][4];
#pragma unroll
    for (int rt = 0; rt < 2; rt++)
#pragma unroll
        for (int ct = 0; ct < 4; ct++) { f32x4 z = {0.f, 0.f, 0.f, 0.f}; acc[rt][ct] = z; }
#pragma unroll
    for (int ks = 0; ks < 2; ks++) {
        f16x8 bfr[4];
#pragma unroll
        for (int ct = 0; ct < 4; ct++)
            bfr[ct] = *(const f16x8*)(smh + 9216 + (ct * 16 + lrow) * 72 + ks * 32 + lk);
#pragma unroll
        for (int rt = 0; rt < 2; rt++) {
            f16x8 av = *(const f16x8*)(smh + (wv * 32 + rt * 16 + lrow) * 72 + ks * 32 + lk);
#pragma unroll
            for (int ct = 0; ct < 4; ct++)
                acc[rt][ct] = __builtin_amdgcn_mfma_f32_16x16x32_f16(av, bfr[ct], acc[rt][ct], 0, 0, 0);
        }
    }
    __syncthreads();  // A/B fully consumed -> overlay with Mt

    // ---- Mt = relu(acc + bias + P[src]) ----
#pragma unroll
    for (int rt = 0; rt < 2; rt++) {
        int chb = wv * 32 + rt * 16 + rbase;
        float4 bv = bv4[rt];
#pragma unroll
        for (int ct = 0; ct < 4; ct++) {
            int edge = ct * 16 + lrow;
            float2 pa = upk(pvr[rt][ct].x), pb = upk(pvr[rt][ct].y);
            f32x4 a = acc[rt][ct];
            Mt[(chb + 0) * 65 + edge] = fmaxf(a[0] + pa.x + bv.x, 0.f);
            Mt[(chb + 1) * 65 + edge] = fmaxf(a[1] + pa.y + bv.y, 0.f);
            Mt[(chb + 2) * 65 + edge] = fmaxf(a[2] + pb.x + bv.z, 0.f);
            Mt[(chb + 3) * 65 + edge] = fmaxf(a[3] + pb.y + bv.w, 0.f);
        }
    }
    __syncthreads();

    // ---- segmented sum: 256 threads = 128 channels x 2 row-halves ----
    {
        int c = tid & 127;
        int h = tid >> 7;
        int rows = min(64, n_edges - t0);
        int r0 = h * 32;
        int r1 = min(rows, r0 + 32);
        if (r0 < r1) {
            int prev_n = h ? nid_s[31] : bound_s[0];
            int next_n = h ? bound_s[1] : ((rows > 32) ? nid_s[32] : bound_s[1]);
            int cur = nid_s[r0];
            int seg_start = r0;
            float run = 0.f;
            for (int r = r0; r < r1; r++) {
                int nd = nid_s[r];
                if (nd != cur) {
                    if (seg_start == r0 && cur == prev_n) atomicAdd(s + (long)cur * 128 + c, run);
                    else s[(long)cur * 128 + c] = run;
                    cur = nd; seg_start = r; run = 0.f;
                }
                run += Mt[c * 65 + r];
            }
            if ((seg_start == r0 && cur == prev_n) || cur == next_n)
                atomicAdd(s + (long)cur * 128 + c, run);
            else s[(long)cur * 128 + c] = run;
        }
    }
}

// ---------------- edge classifier, MFMA + early-gather version (verified) --------------
__global__ __launch_bounds__(256) void k_edge_cls_mfma(
    const float* __restrict__ nSp, const float* __restrict__ nDp,
    const float* __restrict__ eap_g,
    const float* __restrict__ Ctp /*[64 j][32 k2] packed*/,
    const float* __restrict__ b1, const float* __restrict__ w2, const float* __restrict__ b2,
    const int* __restrict__ src, const int* __restrict__ dst,
    const int* __restrict__ uts, const int* __restrict__ tsmax,
    float* __restrict__ logits_out, float4* __restrict__ einfo, int n_edges) {
    __shared__ __align__(16) _Float16 smAB[9216];
    __shared__ int sn_s[64], dn_s[64];
    __shared__ float b1_s[64], w2_s[64], logit_s[64];
    float* Of = (float*)smAB;  // overlay after MFMA
    int tid = threadIdx.x;
    int t0 = blockIdx.x * 64;

    if (tid < 64) {
        int e = min(t0 + tid, n_edges - 1);
        sn_s[tid] = src[e];
        dn_s[tid] = dst[e];
    } else if (tid < 128) {
        b1_s[tid - 64] = b1[tid - 64];
    } else if (tid < 192) {
        w2_s[tid - 128] = w2[tid - 128];
    }
    __syncthreads();

    // ---- early gathers: 4 lanes per edge, 32B each ----
    int el = tid >> 2, q = tid & 3;
    const float4* Sp = (const float4*)(nSp + (long)sn_s[el] * 32) + q * 2;
    float4 sA = Sp[0], sB = Sp[1];
    const float4* Dp = (const float4*)(nDp + (long)dn_s[el] * 32) + q * 2;
    float4 dA = Dp[0], dB = Dp[1];

    // ---- stage A (ea rows) and B (Ct rows) into LDS ----
    const float4* eap4 = (const float4*)eap_g;
    const float4* Ct4 = (const float4*)Ctp;
#pragma unroll
    for (int i = 0; i < 2; i++) {
        int idx = tid + 256 * i;        // 0..511
        int ael = idx >> 3, c = idx & 7;
        int e2 = t0 + ael;
        float4 v = make_float4(0, 0, 0, 0);
        if (e2 < n_edges) v = eap4[(long)e2 * 8 + c];
        *((float4*)(smAB + ael * 72 + c * 8)) = v;
    }
#pragma unroll
    for (int i = 0; i < 2; i++) {
        int idx = tid + 256 * i;        // 0..511
        int j = idx >> 3, c = idx & 7;
        float4 v = Ct4[j * 8 + c];
        *((float4*)(smAB + 4608 + j * 72 + c * 8)) = v;
    }
    __syncthreads();

    int lane = tid & 63;
    int wv = tid >> 6;
    int lrow = lane & 15;
    int lk = (lane >> 4) << 3;
    int rbase = (lane >> 4) << 2;
    f32x4 acc[4];
#pragma unroll
    for (int ct = 0; ct < 4; ct++) { f32x4 z = {0.f, 0.f, 0.f, 0.f}; acc[ct] = z; }
#pragma unroll
    for (int ks = 0; ks < 2; ks++) {
        f16x8 av = *(const f16x8*)(smAB + (wv * 16 + lrow) * 72 + ks * 32 + lk);
#pragma unroll
        for (int ct = 0; ct < 4; ct++) {
            f16x8 bv = *(const f16x8*)(smAB + 4608 + (ct * 16 + lrow) * 72 + ks * 32 + lk);
            acc[ct] = __builtin_amdgcn_mfma_f32_16x16x32_f16(av, bv, acc[ct], 0, 0, 0);
        }
    }
    __syncthreads();  // all A/B reads done -> overlay with O

#pragma unroll
    for (int ct = 0; ct < 4; ct++)
#pragma unroll
        for (int r = 0; r < 4; r++)
            Of[(wv * 16 + rbase + r) * 68 + ct * 16 + lrow] = acc[ct][r];
    __syncthreads();

    const float* Orow = Of + el * 68 + q * 16;
    const float* sa = (const float*)&sA;
    const float* sb = (const float*)&sB;
    const float* da = (const float*)&dA;
    const float* db = (const float*)&dB;
    float partial = 0.f;
#pragma unroll
    for (int i = 0; i < 4; i++) {
        float2 su = upk(sa[i]), du = upk(da[i]);
        float v0 = fmaxf(b1_s[q * 16 + 2 * i] + su.x + du.x + Orow[2 * i], 0.f);
        float v1 = fmaxf(b1_s[q * 16 + 2 * i + 1] + su.y + du.y + Orow[2 * i + 1], 0.f);
        partial = fmaf(v0, w2_s[q * 16 + 2 * i], partial);
        partial = fmaf(v1, w2_s[q * 16 + 2 * i + 1], partial);
    }
#pragma unroll
    for (int i = 0; i < 4; i++) {
        float2 su = upk(sb[i]), du = upk(db[i]);
        float v0 = fmaxf(b1_s[q * 16 + 8 + 2 * i] + su.x + du.x + Orow[8 + 2 * i], 0.f);
        float v1 = fmaxf(b1_s[q * 16 + 8 + 2 * i + 1] + su.y + du.y + Orow[8 + 2 * i + 1], 0.f);
        partial = fmaf(v0, w2_s[q * 16 + 8 + 2 * i], partial);
        partial = fmaf(v1, w2_s[q * 16 + 8 + 2 * i + 1], partial);
    }
    partial += __shfl_xor(partial, 1);
    partial += __shfl_xor(partial, 2);
    if (q == 0) logit_s[el] = partial;
    __syncthreads();

    if (tid < 64) {
        int e = t0 + tid;
        if (e < n_edges) {
            float logit = logit_s[tid] + b2[0];
            logits_out[e] = logit;
            float p = 1.f / (1.f + expf(-logit));
            float now = (float)(*tsmax);
            float age = fmaxf(now - (float)uts[e], 0.f);
            float decay = expf(-age / 2592000.f);
            einfo[e] = make_float4(p, decay, age, 0.f);
        }
    }
}

// ---------------- ts max reduction -----------------------------------------------------
__global__ void k_tsmax(const int* __restrict__ ts, int* __restrict__ out) {
    int i = blockIdx.x * blockDim.x + threadIdx.x;
    int stride = gridDim.x * blockDim.x;
    int m = 0;
    for (int t = i; t < N_EDGES; t += stride) m = max(m, ts[t]);
#pragma unroll
    for (int off = 32; off > 0; off >>= 1) m = max(m, __shfl_down(m, off));
    if ((threadIdx.x & 63) == 0) atomicMax(out, m);
}

// ---------------- per-node aggregation over dual CSR (no atomics) ----------------------
__global__ __launch_bounds__(256) void k_node_agg(
    const float4* __restrict__ einfo,
    const int* __restrict__ row_d, const int* __restrict__ eid,
    const int* __restrict__ row_s, const int* __restrict__ eid_src,
    float* __restrict__ feat8) {
    int n = blockIdx.x * blockDim.x + threadIdx.x;
    if (n >= N_NODES) return;
    int d0 = row_d[n], d1 = row_d[n + 1];
    int s0 = row_s[n], s1 = row_s[n + 1];
    float cnt = (float)((d1 - d0) + (s1 - s0));
    float sump = 0.f, maxp = 0.f, sumh = 0.f, sumpd = 0.f, sumd = 0.f;
    float sumh30 = 0.f, maxp30 = 0.f, sump30 = 0.f, suml30 = 0.f, minage = 9999.f;
#pragma unroll 1
    for (int pass = 0; pass < 2; pass++) {
        int a = pass ? s0 : d0, b = pass ? s1 : d1;
        const int* lst = pass ? eid_src : eid;
        for (int idx = a; idx < b; idx++) {
            float4 v = einfo[lst[idx]];
            float p = v.x, decay = v.y, age = v.z;
            float aged = age / 86400.f;
            bool high = p >= 0.7f;
            bool l30 = age <= 2592000.f;
            sump += p;
            maxp = fmaxf(maxp, p);
            sumpd += p * decay;
            sumd += decay;
            if (high) {
                sumh += 1.f;
                minage = fminf(minage, aged);
            }
            if (l30) {
                sump30 += p;
                suml30 += 1.f;
                maxp30 = fmaxf(maxp30, p);
                if (high) sumh30 += 1.f;
            }
        }
    }
    float* f = feat8 + (long)n * 8;
    f[0] = sump / (cnt + 1e-6f);
    f[1] = maxp;
    f[2] = log1pf(sumh);
    f[3] = sumpd / (sumd + 1e-6f);
    f[4] = log1pf(sumh30);
    f[5] = maxp30;
    f[6] = sump30 / (suml30 + 1e-6f);
    f[7] = log1pf(fminf(fminf(minage, 9999.f), 90.f)) / log1pf(90.f);
}

// ---------------- node classifier ------------------------------------------------------
__global__ __launch_bounds__(256) void k_node_cls(
    const float* __restrict__ ne, const float* __restrict__ feat8,
    const float* __restrict__ w1t /*[64][72]*/, const float* __restrict__ b1,
    const float* __restrict__ gamma, const float* __restrict__ beta,
    const float* __restrict__ mean, const float* __restrict__ var,
    const float* __restrict__ w2, const float* __restrict__ b2,
    float* __restrict__ out) {
    int n = blockIdx.x * blockDim.x + threadIdx.x;
    if (n >= N_NODES) return;
    float in[72];
    const float4* nr = (const float4*)(ne + (long)n * 64);
#pragma unroll
    for (int i = 0; i < 16; i++) {
        float4 v = nr[i];
        in[4 * i] = v.x; in[4 * i + 1] = v.y; in[4 * i + 2] = v.z; in[4 * i + 3] = v.w;
    }
    const float4* fr = (const float4*)(feat8 + (long)n * 8);
    float4 f0 = fr[0], f1 = fr[1];
    in[64] = f0.x; in[65] = f0.y; in[66] = f0.z; in[67] = f0.w;
    in[68] = f1.x; in[69] = f1.y; in[70] = f1.z; in[71] = f1.w;
    float logit = b2[0];
    for (int j = 0; j < 64; j++) {
        float h = b1[j];
        const float* wr = w1t + j * 72;
#pragma unroll
        for (int k = 0; k < 72; k++) h = fmaf(in[k], wr[k], h);
        h = (h - mean[j]) * rsqrtf(var[j] + 1e-5f) * gamma[j] + beta[j];
        h = fmaxf(h, 0.f);
        logit = fmaf(h, w2[j], logit);
    }
    out[n] = logit;
}

extern "C" void kernel_launch(void* const* d_in, const int* in_sizes, int n_in,
                              void* d_out, int out_size, void* d_ws, size_t ws_size,
                              hipStream_t stream) {
    const float* x = (const float*)d_in[0];
    const int* eidx = (const int*)d_in[1];
    const int* src = eidx;
    const int* dst = eidx + N_EDGES;
    const float* la = (const float*)d_in[2];
    const float* tse = (const float*)d_in[3];
    const int* bp = (const int*)d_in[4];
    const int* tt = (const int*)d_in[5];
    const float* cr = (const float*)d_in[6];
    const float* tsp = (const float*)d_in[7];
    const float* tg = (const float*)d_in[8];
    const float* r7 = (const float*)d_in[9];
    const float* r30 = (const float*)d_in[10];
    const int* uts = (const int*)d_in[11];
    const float* tx_emb = (const float*)d_in[12];
    const float* bank_emb = (const float*)d_in[13];
    const float* ee_w1 = (const float*)d_in[14];
    const float* ee_b1 = (const float*)d_in[15];
    const float* ee_w2 = (const float*)d_in[16];
    const float* ee_b2 = (const float*)d_in[17];
    const float* msg1_w = (const float*)d_in[18];
    const float* msg1_b = (const float*)d_in[19];
    const float* upd1_w = (const float*)d_in[20];
    const float* upd1_b = (const float*)d_in[21];
    const float* msg2_w = (const float*)d_in[22];
    const float* msg2_b = (const float*)d_in[23];
    const float* upd2_w = (const float*)d_in[24];
    const float* upd2_b = (const float*)d_in[25];
    const float* ec_w1 = (const float*)d_in[26];
    const float* ec_b1 = (const float*)d_in[27];
    const float* ec_w2 = (const float*)d_in[28];
    const float* ec_b2 = (const float*)d_in[29];
    const float* nc_w1 = (const float*)d_in[30];
    const float* nc_b1 = (const float*)d_in[31];
    const float* bn_g = (const float*)d_in[32];
    const float* bn_b = (const float*)d_in[33];
    const float* bn_m = (const float*)d_in[34];
    const float* bn_v = (const float*)d_in[35];
    const float* nc_w2 = (const float*)d_in[36];
    const float* nc_b2 = (const float*)d_in[37];

    float* out_node = (float*)d_out;              // [N_NODES]
    float* out_edge = (float*)d_out + N_NODES;    // [N_EDGES]

    // workspace layout (floats)
    float* ws0 = (float*)d_ws;
    float* eap_g = ws0;                          // E*32 packed f16
    float* Pp = eap_g + (long)N_EDGES * 32;      // N*64 packed (einfo alias)
    float* s = Pp + (long)N_NODES * 64;          // N*128 fp32
    float* h1 = s + (long)N_NODES * 128;         // N*128 fp32
    float* ne = h1 + (long)N_NODES * 128;        // N*64 fp32
    float* nSp = ne + (long)N_NODES * 64;        // N*32 packed
    float* nDp = nSp + (long)N_NODES * 32;       // N*32 packed
    float* feat8 = nDp + (long)N_NODES * 32;     // N*8
    float* Ctp = feat8 + (long)N_NODES * 8;      // 64*32
    float* ncw1t = Ctp + 64 * 32;                // 64*72
    int* tsmax = (int*)(ncw1t + 64 * 72);        // 1
    int* degi = tsmax + 1;                       // N  (dst degree)
    int* degs = degi + N_NODES;                  // N  (src degree)
    int* row_d = degs + N_NODES;                 // N+1
    int* row_s = row_d + N_NODES + 1;            // N+1
    int* cur_d = row_s + N_NODES + 1;            // N
    int* cur_s = cur_d + N_NODES;                // N
    int* eid = cur_s + N_NODES;                  // E (dst-sorted)
    int* eid_src = eid + N_EDGES;                // E (src-sorted)
    int* partials = eid_src + N_EDGES;           // 512
    float* W12tp = (float*)(partials + 512);     // 8960 words (W1t 4608 ++ W2t 4352)
    float* Wm1tp = W12tp + 8960;                 // 4608 words
    float* Wm2tp = Wm1tp + 4608;                 // 4608 words
    float4* einfo = (float4*)Pp;                 // aliases Pp (dead after 2nd msg_seg)

    const int EB = (N_EDGES + 255) / 256;
    const int NB = (N_NODES + 255) / 256;        // 196
    const int NB2 = (N_NODES + 63) / 64;         // 782
    const int MB = (N_EDGES + 63) / 64;          // 7813
    const int EEB = (N_EDGES + 64 * EE_TILES - 1) / (64 * EE_TILES);  // 1954

    // ---- init ----
    hipMemsetAsync(tsmax, 0, (size_t)(1 + 2 * N_NODES) * 4, stream);  // tsmax+degi+degs
    hipMemsetAsync(s, 0, (size_t)N_NODES * 128 * 4, stream);

    // ---- dual-CSR build ----
    k_deg_count<<<EB, 256, 0, stream>>>(eidx, degi, degs);
    k_block_sums2<<<dim3(NB, 2), 256, 0, stream>>>(degi, degs, partials, N_NODES);
    k_scan_partials2<<<2, 256, 0, stream>>>(partials, NB);
    k_scan_final2<<<dim3(NB, 2), 256, 0, stream>>>(degi, degs, partials,
                                                   row_d, row_s, cur_d, cur_s, N_NODES);
    k_fill_slots<<<EB, 256, 0, stream>>>(eidx, cur_d, cur_s, eid, eid_src);

    // ---- weight prep (Ct pack + nc_w1 transpose + LDS-ready f16 images) ----
    k_prep_weights<<<97, 256, 0, stream>>>(ec_w1 + 128 * 64, Ctp, nc_w1, ncw1t,
                                           ee_w1, ee_w2, W12tp,
                                           msg1_w + 128 * 128, Wm1tp,
                                           msg2_w + 128 * 128, Wm2tp);

    // ---- edge encoder (MFMA; persistent weights; 4 tiles/block) ----
    k_edge_enc_mfma<<<EEB, 256, 0, stream>>>(la, tse, bp, tt, cr, tsp, tg, r7, r30,
                                             tx_emb, bank_emb, W12tp, ee_b1, ee_b2,
                                             eap_g, N_EDGES);

    // ---- SAGE layer 1 ----
    k_node_gemm_mfma<128, 0, 128, false, false, true><<<NB2, 256, 0, stream>>>(
        x, 128, nullptr, 0, nullptr, msg1_w, 128, nullptr, Pp, 64, N_NODES);
    k_msg_seg_mfma<<<MB, 256, 0, stream>>>(Pp, eap_g, Wm1tp, msg1_b, src, dst, eid, s, N_EDGES);
    k_node_gemm_mfma<128, 128, 128, true, true, false><<<NB2, 256, 0, stream>>>(
        x, 128, s, 128, degi, upd1_w, 128, upd1_b, h1, 128, N_NODES);

    // ---- SAGE layer 2 ----
    k_node_gemm_mfma<128, 0, 128, false, false, true><<<NB2, 256, 0, stream>>>(
        h1, 128, nullptr, 0, nullptr, msg2_w, 128, nullptr, Pp, 64, N_NODES);
    hipMemsetAsync(s, 0, (size_t)N_NODES * 128 * 4, stream);
    k_msg_seg_mfma<<<MB, 256, 0, stream>>>(Pp, eap_g, Wm2tp, msg2_b, src, dst, eid, s, N_EDGES);
    k_node_gemm_mfma<128, 128, 64, true, true, false><<<NB2, 256, 0, stream>>>(
        h1, 128, s, 128, degi, upd2_w, 64, upd2_b, ne, 64, N_NODES);
    // Pp dead from here -> einfo alias safe

    // ---- edge classifier prep: nSp/nDp, 4-way split ----
    k_ec_prep<<<dim3(NB, 4), 256, 0, stream>>>(ne, ec_w1, nSp, nDp);

    // ---- edge classifier (MFMA + early gathers) ----
    k_tsmax<<<256, 256, 0, stream>>>(uts, tsmax);
    k_edge_cls_mfma<<<MB, 256, 0, stream>>>(nSp, nDp, eap_g, Ctp, ec_b1, ec_w2, ec_b2,
                                            src, dst, uts, tsmax, out_edge, einfo, N_EDGES);

    // ---- node aggregation (dual CSR) ----
    k_node_agg<<<NB, 256, 0, stream>>>(einfo, row_d, eid, row_s, eid_src, feat8);

    // ---- node classifier ----
    k_node_cls<<<NB, 256, 0, stream>>>(ne, feat8, ncw1t, nc_b1, bn_g, bn_b, bn_m, bn_v,
                                       nc_w2, nc_b2, out_node);
}

// Round 9
// 721.581 us; speedup vs baseline: 1.0026x; 1.0026x over previous
//
#include <hip/hip_runtime.h>
#include <math.h>

#define N_NODES 50000
#define N_EDGES 500000

// ---------- f16 pair helpers ----------
typedef _Float16 h2_t __attribute__((ext_vector_type(2)));
__device__ inline float pk(float a, float b) {
    h2_t h; h[0] = (_Float16)a; h[1] = (_Float16)b;
    float r; __builtin_memcpy(&r, &h, 4); return r;
}
__device__ inline float2 upk(float p) {
    h2_t h; __builtin_memcpy(&h, &p, 4);
    return make_float2((float)h[0], (float)h[1]);
}

// ---------- MFMA types ----------
typedef _Float16 f16x8 __attribute__((ext_vector_type(8)));
typedef float f32x4 __attribute__((ext_vector_type(4)));

// =================== dual-CSR build (dst-sorted eid + src-sorted eid_src) ==============
__global__ void k_deg_count(const int* __restrict__ eidx,
                            int* __restrict__ degi, int* __restrict__ degs) {
    int i = blockIdx.x * blockDim.x + threadIdx.x;
    if (i < N_EDGES) {
        atomicAdd(degi + eidx[N_EDGES + i], 1);  // dst
        atomicAdd(degs + eidx[i], 1);            // src
    }
}

__global__ void k_block_sums2(const int* __restrict__ degi, const int* __restrict__ degs,
                              int* __restrict__ partials, int n) {
    const int* deg = blockIdx.y ? degs : degi;
    int* part = partials + blockIdx.y * 256;
    __shared__ int sm[256];
    int i = blockIdx.x * 256 + threadIdx.x;
    sm[threadIdx.x] = (i < n) ? deg[i] : 0;
    __syncthreads();
    for (int s = 128; s > 0; s >>= 1) {
        if (threadIdx.x < s) sm[threadIdx.x] += sm[threadIdx.x + s];
        __syncthreads();
    }
    if (threadIdx.x == 0) part[blockIdx.x] = sm[0];
}

__global__ void k_scan_partials2(int* partials, int nb) {
    int* part = partials + blockIdx.x * 256;
    __shared__ int sm[256];
    int v = (threadIdx.x < nb) ? part[threadIdx.x] : 0;
    sm[threadIdx.x] = v;
    __syncthreads();
    for (int off = 1; off < 256; off <<= 1) {
        int t = (threadIdx.x >= off) ? sm[threadIdx.x - off] : 0;
        __syncthreads();
        sm[threadIdx.x] += t;
        __syncthreads();
    }
    if (threadIdx.x < nb) part[threadIdx.x] = sm[threadIdx.x] - v;
}

// also writes the cursor copies. NOTE: cur may alias deg (read-before-write per
// thread, no cross-index access) — the launcher passes cur_s == degs.
__global__ void k_scan_final2(const int* __restrict__ degi, const int* __restrict__ degs,
                              const int* __restrict__ partials,
                              int* __restrict__ row_d, int* __restrict__ row_s,
                              int* __restrict__ cur_d, int* __restrict__ cur_s, int n) {
    const int* deg = blockIdx.y ? degs : degi;
    const int* part = partials + blockIdx.y * 256;
    int* row = blockIdx.y ? row_s : row_d;
    int* cur = blockIdx.y ? cur_s : cur_d;
    __shared__ int sm[256];
    int i = blockIdx.x * 256 + threadIdx.x;
    int v = (i < n) ? deg[i] : 0;
    sm[threadIdx.x] = v;
    __syncthreads();
    for (int off = 1; off < 256; off <<= 1) {
        int t = (threadIdx.x >= off) ? sm[threadIdx.x - off] : 0;
        __syncthreads();
        sm[threadIdx.x] += t;
        __syncthreads();
    }
    if (i < n) {
        int rv = part[blockIdx.x] + sm[threadIdx.x] - v;
        row[i] = rv; cur[i] = rv;
    }
    if (i == n - 1) row[n] = part[blockIdx.x] + sm[threadIdx.x];
}

// also writes islot (edge -> dst-slot), coalesced.
__global__ void k_fill_slots(const int* __restrict__ eidx,
                             int* __restrict__ cur_d, int* __restrict__ cur_s,
                             int* __restrict__ eid, int* __restrict__ eid_src,
                             int* __restrict__ islot) {
    int i = blockIdx.x * blockDim.x + threadIdx.x;
    if (i < N_EDGES) {
        int pd = atomicAdd(cur_d + eidx[N_EDGES + i], 1);
        eid[pd] = i;
        islot[i] = pd;
        int ps = atomicAdd(cur_s + eidx[i], 1);
        eid_src[ps] = i;
    }
}

// ---------------- weight prep: ALL LDS-ready f16 images prepacked ----------------------
// Image layout per 64-K chunk: [c: JC][36 words] (32 kp pairs + 4 pad) — exactly the
// LDS layout, so per-block staging is a linear conflict-free float4 copy.
__device__ inline float pack_img(const float* __restrict__ W, int ldw, int JC, int u) {
    int per = 36 * JC;
    int chunk = u / per, r = u - chunk * per;
    int c = r / 36, w = r - c * 36;
    if (w >= 32) return 0.f;
    return pk(W[(long)(chunk * 64 + 2 * w) * ldw + c],
              W[(long)(chunk * 64 + 2 * w + 1) * ldw + c]);
}

__global__ void k_prep_weights(
    const float* __restrict__ C /*ec rows128..191*/, float* __restrict__ Ctp,
    const float* __restrict__ nc_w1, float* __restrict__ ncw1t,
    const float* __restrict__ ee_w1, const float* __restrict__ ee_w2, float* __restrict__ W12tp,
    const float* __restrict__ m1w, float* __restrict__ Wm1tp,
    const float* __restrict__ m2w, float* __restrict__ Wm2tp,
    const float* __restrict__ msg1_w, float* __restrict__ Wpre1,
    const float* __restrict__ upd1_w, float* __restrict__ Wupd1,
    const float* __restrict__ msg2_w, float* __restrict__ Wpre2,
    const float* __restrict__ upd2_w, float* __restrict__ Wupd2,
    const float* __restrict__ ec_w1, float* __restrict__ Wec) {
    int i = blockIdx.x * 256 + threadIdx.x;
    if (i < 2048) {
        int j = i >> 5, k2 = i & 31;
        Ctp[i] = pk(C[(2 * k2) * 64 + j], C[(2 * k2 + 1) * 64 + j]);
        return;
    }
    int t = i - 2048;
    if (t < 72 * 64) {
        int k = t / 64, j = t - k * 64;
        ncw1t[j * 72 + k] = nc_w1[k * 64 + j];
        return;
    }
    int u = t - 72 * 64;
    if (u < 4608) {                        // edge-enc W1t [128][36]
        int c = u / 36, w = u % 36;
        float v = 0.f;
        if (w < 32) {
            float a = (2 * w < 38) ? ee_w1[(2 * w) * 128 + c] : 0.f;
            float b = (2 * w + 1 < 38) ? ee_w1[(2 * w + 1) * 128 + c] : 0.f;
            v = pk(a, b);
        }
        W12tp[u] = v;
        return;
    }
    u -= 4608;
    if (u < 4352) {                        // edge-enc W2t [64][68]
        int c = u / 68, w = u % 68;
        float v = 0.f;
        if (w < 64) v = pk(ee_w2[(2 * w) * 64 + c], ee_w2[(2 * w + 1) * 64 + c]);
        W12tp[4608 + u] = v;
        return;
    }
    u -= 4352;
    if (u < 4608) { Wm1tp[u] = pack_img(m1w, 128, 128, u); return; }
    u -= 4608;
    if (u < 4608) { Wm2tp[u] = pack_img(m2w, 128, 128, u); return; }
    u -= 4608;
    if (u < 9216) { Wpre1[u] = pack_img(msg1_w, 128, 128, u); return; }
    u -= 9216;
    if (u < 18432) { Wupd1[u] = pack_img(upd1_w, 128, 128, u); return; }
    u -= 18432;
    if (u < 9216) { Wpre2[u] = pack_img(msg2_w, 128, 128, u); return; }
    u -= 9216;
    if (u < 9216) { Wupd2[u] = pack_img(upd2_w, 64, 64, u); return; }
    u -= 9216;
    if (u < 4608) {                        // Wec: [c:128][36]; c<64 -> src half, c>=64 -> dst half
        int c = u / 36, w = u % 36;
        float v = 0.f;
        if (w < 32) {
            if (c < 64) v = pk(ec_w1[(2 * w) * 64 + c], ec_w1[(2 * w + 1) * 64 + c]);
            else v = pk(ec_w1[(64 + 2 * w) * 64 + (c - 64)], ec_w1[(64 + 2 * w + 1) * 64 + (c - 64)]);
        }
        Wec[u] = v;
    }
}

// ---------------- edge encoder, MFMA + persistent weights + 4 tiles/block --------------
// Output written in DST-SLOT order: eap[islot[e]] (scattered 128B rows) so that both
// msg_seg dispatches read ea as a linear stream; edge_cls absorbs the one gather.
#define EE_TILES 4
#define EE_W1O 0
#define EE_W2O 9216
#define EE_TO 17920
#define EE_SMH2 26624

__global__ __launch_bounds__(256) void k_edge_enc_mfma(
    const float* __restrict__ la, const float* __restrict__ tse,
    const int* __restrict__ bp, const int* __restrict__ tt,
    const float* __restrict__ cr, const float* __restrict__ tsp,
    const float* __restrict__ tg, const float* __restrict__ r7,
    const float* __restrict__ r30,
    const float* __restrict__ tx_emb, const float* __restrict__ bank_emb,
    const float* __restrict__ W12tp, const float* __restrict__ eb1,
    const float* __restrict__ eb2, const int* __restrict__ islot,
    float* __restrict__ eap /*E x 32, slot-ordered*/, int n_edges) {
    __shared__ __align__(16) _Float16 sm[EE_SMH2];
    __shared__ int isl_s[64];
    float* smf = (float*)sm;  // word view
    int tid = threadIdx.x;

    // ---- stage W1t+W2t once: 2240 float4s, linear (conflict-free) ----
    {
        const float4* Wg = (const float4*)W12tp;
        float4* Wl = (float4*)sm;
#pragma unroll
        for (int i = 0; i < 9; i++) {
            int idx = tid + 256 * i;
            if (idx < 2240) Wl[idx] = Wg[idx];
        }
    }

    int lane = tid & 63;
    int wv = tid >> 6;
    int lrow = lane & 15;
    int lk = (lane >> 4) << 3;
    int rbase = (lane >> 4) << 2;

#pragma unroll 1
    for (int tile = 0; tile < EE_TILES; tile++) {
        int t0 = (blockIdx.x * EE_TILES + tile) * 64;
        if (t0 >= n_edges) break;
        __syncthreads();  // weights staged / prev tile copy-out done

        // ---- feature build into F @ word 8960, stride 36 words; stage isl ----
        if (tid < 64) isl_s[tid] = (t0 + tid < n_edges) ? islot[t0 + tid] : 0;
        {
            int el = tid & 63, g = tid >> 6;
            int e = t0 + el;
            bool ok = e < n_edges;
            float* Fr = smf + 8960 + el * 36;
            if (g == 0) {
                Fr[0] = ok ? pk(la[e], cr[e]) : 0.f;
                Fr[1] = ok ? pk(tsp[e], tg[e]) : 0.f;
                Fr[2] = ok ? pk(r7[e], r30[e]) : 0.f;
#pragma unroll
                for (int z = 19; z < 32; z++) Fr[z] = 0.f;  // K pad -> zero
            } else if (g == 1) {
                float4 a = make_float4(0, 0, 0, 0), b = a;
                if (ok) { a = ((const float4*)(tse + (long)e * 8))[0];
                          b = ((const float4*)(tse + (long)e * 8))[1]; }
                Fr[3] = pk(a.x, a.y); Fr[4] = pk(a.z, a.w);
                Fr[5] = pk(b.x, b.y); Fr[6] = pk(b.z, b.w);
            } else if (g == 2) {
                float4 a = make_float4(0, 0, 0, 0), b = a;
                if (ok) { int txi = tt[e];
                          a = ((const float4*)(tx_emb + (long)txi * 8))[0];
                          b = ((const float4*)(tx_emb + (long)txi * 8))[1]; }
                Fr[7] = pk(a.x, a.y); Fr[8] = pk(a.z, a.w);
                Fr[9] = pk(b.x, b.y); Fr[10] = pk(b.z, b.w);
            } else {
                float4 a = make_float4(0, 0, 0, 0), b = a, c = a, d = a;
                if (ok) {
                    int bk0 = bp[e * 2 + 0], bk1 = bp[e * 2 + 1];
                    a = ((const float4*)(bank_emb + (long)bk0 * 8))[0];
                    b = ((const float4*)(bank_emb + (long)bk0 * 8))[1];
                    c = ((const float4*)(bank_emb + (long)bk1 * 8))[0];
                    d = ((const float4*)(bank_emb + (long)bk1 * 8))[1];
                }
                Fr[11] = pk(a.x, a.y); Fr[12] = pk(a.z, a.w);
                Fr[13] = pk(b.x, b.y); Fr[14] = pk(b.z, b.w);
                Fr[15] = pk(c.x, c.y); Fr[16] = pk(c.z, c.w);
                Fr[17] = pk(d.x, d.y); Fr[18] = pk(d.z, d.w);
            }
        }
        __syncthreads();

        // ---- GEMM1 ----
        f16x8 a0 = *(const f16x8*)(sm + EE_TO + (wv * 16 + lrow) * 72 + lk);
        f16x8 a1 = *(const f16x8*)(sm + EE_TO + (wv * 16 + lrow) * 72 + 32 + lk);
        f32x4 acc[8];
#pragma unroll
        for (int ct = 0; ct < 8; ct++) {
            const _Float16* wb = sm + EE_W1O + (ct * 16 + lrow) * 72 + lk;
            f16x8 b0 = *(const f16x8*)(wb);
            f16x8 b1 = *(const f16x8*)(wb + 32);
            f32x4 z = {0.f, 0.f, 0.f, 0.f};
            acc[ct] = __builtin_amdgcn_mfma_f32_16x16x32_f16(a0, b0, z, 0, 0, 0);
            acc[ct] = __builtin_amdgcn_mfma_f32_16x16x32_f16(a1, b1, acc[ct], 0, 0, 0);
        }
        __syncthreads();  // F consumed -> overlay with H

        // ---- bias + relu -> H (f16, stride 136 hw) ----
#pragma unroll
        for (int ct = 0; ct < 8; ct++) {
            int col = ct * 16 + lrow;
            float bias = eb1[col];
#pragma unroll
            for (int r = 0; r < 4; r++) {
                int row = wv * 16 + rbase + r;
                sm[EE_TO + row * 136 + col] = (_Float16)fmaxf(acc[ct][r] + bias, 0.f);
            }
        }
        __syncthreads();

        // ---- GEMM2 ----
        f32x4 acc2[4];
#pragma unroll
        for (int ct = 0; ct < 4; ct++) { f32x4 z = {0.f, 0.f, 0.f, 0.f}; acc2[ct] = z; }
#pragma unroll
        for (int ks = 0; ks < 4; ks++) {
            f16x8 av = *(const f16x8*)(sm + EE_TO + (wv * 16 + lrow) * 136 + ks * 32 + lk);
#pragma unroll
            for (int ct = 0; ct < 4; ct++) {
                f16x8 bv = *(const f16x8*)(sm + EE_W2O + (ct * 16 + lrow) * 136 + ks * 32 + lk);
                acc2[ct] = __builtin_amdgcn_mfma_f32_16x16x32_f16(av, bv, acc2[ct], 0, 0, 0);
            }
        }
        __syncthreads();  // H consumed -> overlay with O

        // ---- bias -> O (f16, stride 72 hw, pair order == eap layout) ----
#pragma unroll
        for (int ct = 0; ct < 4; ct++) {
            int col = ct * 16 + lrow;
            float bias = eb2[col];
#pragma unroll
            for (int r = 0; r < 4; r++) {
                int row = wv * 16 + rbase + r;
                sm[EE_TO + row * 72 + col] = (_Float16)(acc2[ct][r] + bias);
            }
        }
        __syncthreads();

        // ---- copy-out to slot position: dword-per-thread (conflict-free LDS reads) ----
#pragma unroll
        for (int rep = 0; rep < 8; rep++) {
            int idx = rep * 256 + tid;     // 0..2047 words
            int el = idx >> 5, w = idx & 31;
            int e = t0 + el;
            if (e < n_edges)
                eap[(long)isl_s[el] * 32 + w] = smf[8960 + el * 36 + w];
        }
    }
}

// ---------------- node-level GEMM via MFMA, prepacked W images -------------------------
template <int K1, int K2, int JC, bool RELU, bool DIV2, bool PACKOUT>
__global__ __launch_bounds__(256) void k_node_gemm_mfma(
    const float* __restrict__ in1, int ld1,
    const float* __restrict__ in2, int ld2,
    const int* __restrict__ degv,
    const float* __restrict__ Wimg,   // per-chunk [JC][36] words, prepacked
    const float* __restrict__ bias,
    float* __restrict__ out, int ldo, int nrows) {
    constexpr int NC = (K1 + K2) / 64;
    constexpr int NCT = JC / 16;
    constexpr int AB_HW = 4608 + JC * 72;
    constexpr int OUT_HW = PACKOUT ? 64 * (JC + 8) : 64 * (JC + 4) * 2;
    constexpr int SM_HW = AB_HW > OUT_HW ? AB_HW : OUT_HW;
    __shared__ __align__(16) _Float16 sm[SM_HW];
    float* smw = (float*)sm;  // u32 word view
    int tid = threadIdx.x;
    int t0 = blockIdx.x * 64;

    int lane = tid & 63, wv = tid >> 6;
    int lrow = lane & 15, lk = (lane >> 4) << 3, rbase = (lane >> 4) << 2;

    f32x4 acc[NCT];
#pragma unroll
    for (int ct = 0; ct < NCT; ct++) {
        float b = bias ? bias[ct * 16 + lrow] : 0.f;
        f32x4 v = {b, b, b, b};
        acc[ct] = v;
    }

#pragma unroll 1
    for (int kc = 0; kc < NC; kc++) {
        __syncthreads();
        // ---- stage A chunk (coalesced float4, f16 into [64][72]) ----
        {
            const float* src = (kc * 64 < K1) ? in1 : in2;
            int ld = (kc * 64 < K1) ? ld1 : ld2;
            int ko = (kc * 64 < K1) ? kc * 64 : kc * 64 - K1;
            bool isdiv = DIV2 && (kc * 64 >= K1);
#pragma unroll
            for (int i = 0; i < 4; i++) {
                int f = tid + 256 * i;         // float4 id 0..1023
                int row = f >> 4, c4 = f & 15;
                int grow = t0 + row;
                float4 v = make_float4(0, 0, 0, 0);
                if (grow < nrows) {
                    v = *(const float4*)(src + (long)grow * ld + ko + c4 * 4);
                    if (isdiv) {
                        float dv = 1.f / ((float)degv[grow] + 1e-6f);
                        v.x *= dv; v.y *= dv; v.z *= dv; v.w *= dv;
                    }
                }
                float2 o; o.x = pk(v.x, v.y); o.y = pk(v.z, v.w);
                *((float2*)(sm + row * 72 + c4 * 4)) = o;
            }
        }
        // ---- stage W chunk: linear float4 copy from prepacked image ----
        {
            const float4* Wg = (const float4*)(Wimg + (long)kc * (36 * JC));
            float4* Wl = (float4*)(smw + 2304);
            constexpr int NF4 = 36 * JC / 4;
            constexpr int NI = (NF4 + 255) / 256;
#pragma unroll
            for (int i = 0; i < NI; i++) {
                int idx = tid + 256 * i;
                if (idx < NF4) Wl[idx] = Wg[idx];
            }
        }
        __syncthreads();
        // ---- MFMA: 2 k-steps x NCT col-tiles ----
        f16x8 a0 = *(const f16x8*)(sm + (wv * 16 + lrow) * 72 + lk);
        f16x8 a1 = *(const f16x8*)(sm + (wv * 16 + lrow) * 72 + 32 + lk);
#pragma unroll
        for (int ct = 0; ct < NCT; ct++) {
            const _Float16* wb = sm + 4608 + (ct * 16 + lrow) * 72 + lk;
            f16x8 b0 = *(const f16x8*)(wb);
            f16x8 b1 = *(const f16x8*)(wb + 32);
            acc[ct] = __builtin_amdgcn_mfma_f32_16x16x32_f16(a0, b0, acc[ct], 0, 0, 0);
            acc[ct] = __builtin_amdgcn_mfma_f32_16x16x32_f16(a1, b1, acc[ct], 0, 0, 0);
        }
    }
    __syncthreads();

    if constexpr (PACKOUT) {
#pragma unroll
        for (int ct = 0; ct < NCT; ct++) {
            int col = ct * 16 + lrow;
#pragma unroll
            for (int r = 0; r < 4; r++) {
                float v = acc[ct][r];
                if (RELU) v = fmaxf(v, 0.f);
                sm[(wv * 16 + rbase + r) * (JC + 8) + col] = (_Float16)v;
            }
        }
        __syncthreads();
        constexpr int F4R = JC / 8;
        constexpr int NO = 64 * F4R / 256;
#pragma unroll
        for (int i = 0; i < NO; i++) {
            int idx = tid + 256 * i;
            int row = idx / F4R, c4 = idx % F4R;
            int grow = t0 + row;
            if (grow < nrows) {
                float4 v = *(const float4*)(sm + row * (JC + 8) + c4 * 8);
                *((float4*)(out + (long)grow * ldo + c4 * 4)) = v;
            }
        }
    } else {
        float* Of = smw;  // f32 [64][JC+4]
#pragma unroll
        for (int ct = 0; ct < NCT; ct++) {
            int col = ct * 16 + lrow;
#pragma unroll
            for (int r = 0; r < 4; r++) {
                float v = acc[ct][r];
                if (RELU) v = fmaxf(v, 0.f);
                Of[(wv * 16 + rbase + r) * (JC + 4) + col] = v;
            }
        }
        __syncthreads();
        constexpr int F4R = JC / 4;
        constexpr int NO = 64 * F4R / 256;
#pragma unroll
        for (int i = 0; i < NO; i++) {
            int idx = tid + 256 * i;
            int row = idx / F4R, c4 = idx % F4R;
            int grow = t0 + row;
            if (grow < nrows) {
                float4 v = *(const float4*)(Of + row * (JC + 4) + c4 * 4);
                *((float4*)(out + (long)grow * ldo + c4 * 4)) = v;
            }
        }
    }
}

// ---------------- msg GEMM via MFMA + segmented sum ------------------------------------
// ea slot-ordered -> staging is a LINEAR STREAM (was 64MB random gather/dispatch).
// Staging uses dword-per-thread mapping -> all 32 banks (2-way, free).
__global__ __launch_bounds__(256) void k_msg_seg_mfma(
    const float* __restrict__ Pp /*N x 64 packed*/, const float* __restrict__ eap,
    const float* __restrict__ Wt_g /*4608 words*/, const float* __restrict__ bias,
    const int* __restrict__ src, const int* __restrict__ dst,
    const int* __restrict__ eid,
    float* __restrict__ s, int n_edges) {
    __shared__ __align__(16) float smem[8320];   // Mt f32[128][65]
    _Float16* smh = (_Float16*)smem;
    float* Mt = smem;
    __shared__ int sn_s[64];
    __shared__ int nid_s[64];
    __shared__ int bound_s[2];
    int tid = threadIdx.x;
    int t0 = blockIdx.x * 64;

    if (tid < 64) {
        int slot = t0 + tid;
        int e = (slot < n_edges) ? eid[slot] : 0;
        sn_s[tid] = src[e];
        nid_s[tid] = (slot < n_edges) ? dst[e] : -1;
    }
    if (tid == 64) bound_s[0] = (t0 > 0) ? dst[eid[t0 - 1]] : -1;
    if (tid == 65) bound_s[1] = (t0 + 64 < n_edges) ? dst[eid[t0 + 64]] : -1;

    // ---- stage W^T: linear float4 copy (conflict-free, coalesced) ----
    {
        const float4* Wg = (const float4*)Wt_g;
        float4* Wl = (float4*)smem;
#pragma unroll
        for (int i = 0; i < 5; i++) {
            int idx = tid + 256 * i;
            if (idx < 1152) Wl[idx] = Wg[idx];
        }
    }
    __syncthreads();

    int lane = tid & 63;
    int wv = tid >> 6;
    int lrow = lane & 15;
    int lk = (lane >> 4) << 3;
    int rbase = (lane >> 4) << 2;

    // ---- early P gathers + bias (consumed after MFMA) ----
    int srcs[4];
#pragma unroll
    for (int ct = 0; ct < 4; ct++) srcs[ct] = sn_s[ct * 16 + lrow];
    float2 pvr[2][4];
    float4 bv4[2];
#pragma unroll
    for (int rt = 0; rt < 2; rt++) {
        int chb = wv * 32 + rt * 16 + rbase;
        bv4[rt] = *(const float4*)(bias + chb);
#pragma unroll
        for (int ct = 0; ct < 4; ct++)
            pvr[rt][ct] = *(const float2*)(Pp + (long)srcs[ct] * 64 + (chb >> 1));
    }

    // ---- stage ea rows: LINEAR stream, dword writes (all 32 banks) ----
#pragma unroll
    for (int i = 0; i < 8; i++) {
        int idx = tid + 256 * i;        // 0..2047 words
        int el = idx >> 5, w = idx & 31;
        int e2 = t0 + el;
        float v = 0.f;
        if (e2 < n_edges) v = eap[(long)e2 * 32 + w];
        smem[4608 + el * 36 + w] = v;
    }
    __syncthreads();

    // ---- MFMA: wave wv owns channels wv*32..+31 (2 row-tiles) x 4 edge col-tiles ----
    f32x4 acc[2][4];
#pragma unroll
    for (int rt = 0; rt < 2; rt++)
#pragma unroll
        for (int ct = 0; ct < 4; ct++) { f32x4 z = {0.f, 0.f, 0.f, 0.f}; acc[rt][ct] = z; }
#pragma unroll
    for (int ks = 0; ks < 2; ks++) {
        f16x8 bfr[4];
#pragma unroll
        for (int ct = 0; ct < 4; ct++)
            bfr[ct] = *(const f16x8*)(smh + 9216 + (ct * 16 + lrow) * 72 + ks * 32 + lk);
#pragma unroll
        for (int rt = 0; rt < 2; rt++) {
            f16x8 av = *(const f16x8*)(smh + (wv * 32 + rt * 16 + lrow) * 72 + ks * 32 + lk);
#pragma unroll
            for (int ct = 0; ct < 4; ct++)
                acc[rt][ct] = __builtin_amdgcn_mfma_f32_16x16x32_f16(av, bfr[ct], acc[rt][ct], 0, 0, 0);
        }
    }
    __syncthreads();  // A/B consumed -> overlay with Mt

    // ---- Mt = relu(acc + bias + P[src]) ----
#pragma unroll
    for (int rt = 0; rt < 2; rt++) {
        int chb = wv * 32 + rt * 16 + rbase;
        float4 bv = bv4[rt];
#pragma unroll
        for (int ct = 0; ct < 4; ct++) {
            int edge = ct * 16 + lrow;
            float2 pa = upk(pvr[rt][ct].x), pb = upk(pvr[rt][ct].y);
            f32x4 a = acc[rt][ct];
            Mt[(chb + 0) * 65 + edge] = fmaxf(a[0] + pa.x + bv.x, 0.f);
            Mt[(chb + 1) * 65 + edge] = fmaxf(a[1] + pa.y + bv.y, 0.f);
            Mt[(chb + 2) * 65 + edge] = fmaxf(a[2] + pb.x + bv.z, 0.f);
            Mt[(chb + 3) * 65 + edge] = fmaxf(a[3] + pb.y + bv.w, 0.f);
        }
    }
    __syncthreads();

    // ---- segmented sum: 256 threads = 128 channels x 2 row-halves ----
    {
        int c = tid & 127;
        int h = tid >> 7;
        int rows = min(64, n_edges - t0);
        int r0 = h * 32;
        int r1 = min(rows, r0 + 32);
        if (r0 < r1) {
            int prev_n = h ? nid_s[31] : bound_s[0];
            int next_n = h ? bound_s[1] : ((rows > 32) ? nid_s[32] : bound_s[1]);
            int cur = nid_s[r0];
            int seg_start = r0;
            float run = 0.f;
            for (int r = r0; r < r1; r++) {
                int nd = nid_s[r];
                if (nd != cur) {
                    if (seg_start == r0 && cur == prev_n) atomicAdd(s + (long)cur * 128 + c, run);
                    else s[(long)cur * 128 + c] = run;
                    cur = nd; seg_start = r; run = 0.f;
                }
                run += Mt[c * 65 + r];
            }
            if ((seg_start == r0 && cur == prev_n) || cur == next_n)
                atomicAdd(s + (long)cur * 128 + c, run);
            else s[(long)cur * 128 + c] = run;
        }
    }
}

// ---------------- edge classifier, MFMA + early gathers; ea gathered via islot ---------
__global__ __launch_bounds__(256) void k_edge_cls_mfma(
    const float* __restrict__ nSDp /*N x 64 (32 src-pk + 32 dst-pk)*/,
    const float* __restrict__ eap /*slot-ordered*/, const int* __restrict__ islot,
    const float* __restrict__ Ctp /*[64 j][32 k2] packed*/,
    const float* __restrict__ b1, const float* __restrict__ w2, const float* __restrict__ b2,
    const int* __restrict__ src, const int* __restrict__ dst,
    const int* __restrict__ uts, const int* __restrict__ tsmax,
    float* __restrict__ logits_out, float4* __restrict__ einfo, int n_edges) {
    __shared__ __align__(16) _Float16 smAB[9216];
    __shared__ int sn_s[64], dn_s[64], isl_s[64];
    __shared__ float b1_s[64], w2_s[64], logit_s[64];
    float* Of = (float*)smAB;  // overlay after MFMA
    float* smABw = (float*)smAB;
    int tid = threadIdx.x;
    int t0 = blockIdx.x * 64;

    if (tid < 64) {
        int e = min(t0 + tid, n_edges - 1);
        sn_s[tid] = src[e];
        dn_s[tid] = dst[e];
        isl_s[tid] = islot[e];
    } else if (tid < 128) {
        b1_s[tid - 64] = b1[tid - 64];
    } else if (tid < 192) {
        w2_s[tid - 128] = w2[tid - 128];
    }
    __syncthreads();

    // ---- early gathers: 4 lanes per edge, 32B each ----
    int el = tid >> 2, q = tid & 3;
    const float4* Sp = (const float4*)(nSDp + (long)sn_s[el] * 64) + q * 2;
    float4 sA = Sp[0], sB = Sp[1];
    const float4* Dp = (const float4*)(nSDp + (long)dn_s[el] * 64 + 32) + q * 2;
    float4 dA = Dp[0], dB = Dp[1];

    // ---- stage A (ea rows, gathered via islot) and B (Ct), dword writes ----
#pragma unroll
    for (int i = 0; i < 8; i++) {
        int idx = tid + 256 * i;        // 0..2047 words
        int ael = idx >> 5, w = idx & 31;
        int e2 = t0 + ael;
        float v = 0.f;
        if (e2 < n_edges) v = eap[(long)isl_s[ael] * 32 + w];
        smABw[ael * 36 + w] = v;
    }
#pragma unroll
    for (int i = 0; i < 8; i++) {
        int idx = tid + 256 * i;        // 0..2047 words
        int j = idx >> 5, w = idx & 31;
        smABw[2304 + j * 36 + w] = Ctp[j * 32 + w];
    }
    __syncthreads();

    int lane = tid & 63;
    int wv = tid >> 6;
    int lrow = lane & 15;
    int lk = (lane >> 4) << 3;
    int rbase = (lane >> 4) << 2;
    f32x4 acc[4];
#pragma unroll
    for (int ct = 0; ct < 4; ct++) { f32x4 z = {0.f, 0.f, 0.f, 0.f}; acc[ct] = z; }
#pragma unroll
    for (int ks = 0; ks < 2; ks++) {
        f16x8 av = *(const f16x8*)(smAB + (wv * 16 + lrow) * 72 + ks * 32 + lk);
#pragma unroll
        for (int ct = 0; ct < 4; ct++) {
            f16x8 bv = *(const f16x8*)(smAB + 4608 + (ct * 16 + lrow) * 72 + ks * 32 + lk);
            acc[ct] = __builtin_amdgcn_mfma_f32_16x16x32_f16(av, bv, acc[ct], 0, 0, 0);
        }
    }
    __syncthreads();  // A/B reads done -> overlay with O

#pragma unroll
    for (int ct = 0; ct < 4; ct++)
#pragma unroll
        for (int r = 0; r < 4; r++)
            Of[(wv * 16 + rbase + r) * 68 + ct * 16 + lrow] = acc[ct][r];
    __syncthreads();

    const float* Orow = Of + el * 68 + q * 16;
    const float* sa = (const float*)&sA;
    const float* sb = (const float*)&sB;
    const float* da = (const float*)&dA;
    const float* db = (const float*)&dB;
    float partial = 0.f;
#pragma unroll
    for (int i = 0; i < 4; i++) {
        float2 su = upk(sa[i]), du = upk(da[i]);
        float v0 = fmaxf(b1_s[q * 16 + 2 * i] + su.x + du.x + Orow[2 * i], 0.f);
        float v1 = fmaxf(b1_s[q * 16 + 2 * i + 1] + su.y + du.y + Orow[2 * i + 1], 0.f);
        partial = fmaf(v0, w2_s[q * 16 + 2 * i], partial);
        partial = fmaf(v1, w2_s[q * 16 + 2 * i + 1], partial);
    }
#pragma unroll
    for (int i = 0; i < 4; i++) {
        float2 su = upk(sb[i]), du = upk(db[i]);
        float v0 = fmaxf(b1_s[q * 16 + 8 + 2 * i] + su.x + du.x + Orow[8 + 2 * i], 0.f);
        float v1 = fmaxf(b1_s[q * 16 + 8 + 2 * i + 1] + su.y + du.y + Orow[8 + 2 * i + 1], 0.f);
        partial = fmaf(v0, w2_s[q * 16 + 8 + 2 * i], partial);
        partial = fmaf(v1, w2_s[q * 16 + 8 + 2 * i + 1], partial);
    }
    partial += __shfl_xor(partial, 1);
    partial += __shfl_xor(partial, 2);
    if (q == 0) logit_s[el] = partial;
    __syncthreads();

    if (tid < 64) {
        int e = t0 + tid;
        if (e < n_edges) {
            float logit = logit_s[tid] + b2[0];
            logits_out[e] = logit;
            float p = 1.f / (1.f + expf(-logit));
            float now = (float)(*tsmax);
            float age = fmaxf(now - (float)uts[e], 0.f);
            float decay = expf(-age / 2592000.f);
            einfo[e] = make_float4(p, decay, age, 0.f);
        }
    }
}

// ---------------- ts max reduction -----------------------------------------------------
__global__ void k_tsmax(const int* __restrict__ ts, int* __restrict__ out) {
    int i = blockIdx.x * blockDim.x + threadIdx.x;
    int stride = gridDim.x * blockDim.x;
    int m = 0;
    for (int t = i; t < N_EDGES; t += stride) m = max(m, ts[t]);
#pragma unroll
    for (int off = 32; off > 0; off >>= 1) m = max(m, __shfl_down(m, off));
    if ((threadIdx.x & 63) == 0) atomicMax(out, m);
}

// ---------------- per-node aggregation over dual CSR (no atomics) ----------------------
__global__ __launch_bounds__(256) void k_node_agg(
    const float4* __restrict__ einfo,
    const int* __restrict__ row_d, const int* __restrict__ eid,
    const int* __restrict__ row_s, const int* __restrict__ eid_src,
    float* __restrict__ feat8) {
    int n = blockIdx.x * blockDim.x + threadIdx.x;
    if (n >= N_NODES) return;
    int d0 = row_d[n], d1 = row_d[n + 1];
    int s0 = row_s[n], s1 = row_s[n + 1];
    float cnt = (float)((d1 - d0) + (s1 - s0));
    float sump = 0.f, maxp = 0.f, sumh = 0.f, sumpd = 0.f, sumd = 0.f;
    float sumh30 = 0.f, maxp30 = 0.f, sump30 = 0.f, suml30 = 0.f, minage = 9999.f;
#pragma unroll 1
    for (int pass = 0; pass < 2; pass++) {
        int a = pass ? s0 : d0, b = pass ? s1 : d1;
        const int* lst = pass ? eid_src : eid;
        for (int idx = a; idx < b; idx++) {
            float4 v = einfo[lst[idx]];
            float p = v.x, decay = v.y, age = v.z;
            float aged = age / 86400.f;
            bool high = p >= 0.7f;
            bool l30 = age <= 2592000.f;
            sump += p;
            maxp = fmaxf(maxp, p);
            sumpd += p * decay;
            sumd += decay;
            if (high) {
                sumh += 1.f;
                minage = fminf(minage, aged);
            }
            if (l30) {
                sump30 += p;
                suml30 += 1.f;
                maxp30 = fmaxf(maxp30, p);
                if (high) sumh30 += 1.f;
            }
        }
    }
    float* f = feat8 + (long)n * 8;
    f[0] = sump / (cnt + 1e-6f);
    f[1] = maxp;
    f[2] = log1pf(sumh);
    f[3] = sumpd / (sumd + 1e-6f);
    f[4] = log1pf(sumh30);
    f[5] = maxp30;
    f[6] = sump30 / (suml30 + 1e-6f);
    f[7] = log1pf(fminf(fminf(minage, 9999.f), 90.f)) / log1pf(90.f);
}

// ---------------- node classifier ------------------------------------------------------
__global__ __launch_bounds__(256) void k_node_cls(
    const float* __restrict__ ne, const float* __restrict__ feat8,
    const float* __restrict__ w1t /*[64][72]*/, const float* __restrict__ b1,
    const float* __restrict__ gamma, const float* __restrict__ beta,
    const float* __restrict__ mean, const float* __restrict__ var,
    const float* __restrict__ w2, const float* __restrict__ b2,
    float* __restrict__ out) {
    int n = blockIdx.x * blockDim.x + threadIdx.x;
    if (n >= N_NODES) return;
    float in[72];
    const float4* nr = (const float4*)(ne + (long)n * 64);
#pragma unroll
    for (int i = 0; i < 16; i++) {
        float4 v = nr[i];
        in[4 * i] = v.x; in[4 * i + 1] = v.y; in[4 * i + 2] = v.z; in[4 * i + 3] = v.w;
    }
    const float4* fr = (const float4*)(feat8 + (long)n * 8);
    float4 f0 = fr[0], f1 = fr[1];
    in[64] = f0.x; in[65] = f0.y; in[66] = f0.z; in[67] = f0.w;
    in[68] = f1.x; in[69] = f1.y; in[70] = f1.z; in[71] = f1.w;
    float logit = b2[0];
    for (int j = 0; j < 64; j++) {
        float h = b1[j];
        const float* wr = w1t + j * 72;
#pragma unroll
        for (int k = 0; k < 72; k++) h = fmaf(in[k], wr[k], h);
        h = (h - mean[j]) * rsqrtf(var[j] + 1e-5f) * gamma[j] + beta[j];
        h = fmaxf(h, 0.f);
        logit = fmaf(h, w2[j], logit);
    }
    out[n] = logit;
}

extern "C" void kernel_launch(void* const* d_in, const int* in_sizes, int n_in,
                              void* d_out, int out_size, void* d_ws, size_t ws_size,
                              hipStream_t stream) {
    const float* x = (const float*)d_in[0];
    const int* eidx = (const int*)d_in[1];
    const int* src = eidx;
    const int* dst = eidx + N_EDGES;
    const float* la = (const float*)d_in[2];
    const float* tse = (const float*)d_in[3];
    const int* bp = (const int*)d_in[4];
    const int* tt = (const int*)d_in[5];
    const float* cr = (const float*)d_in[6];
    const float* tsp = (const float*)d_in[7];
    const float* tg = (const float*)d_in[8];
    const float* r7 = (const float*)d_in[9];
    const float* r30 = (const float*)d_in[10];
    const int* uts = (const int*)d_in[11];
    const float* tx_emb = (const float*)d_in[12];
    const float* bank_emb = (const float*)d_in[13];
    const float* ee_w1 = (const float*)d_in[14];
    const float* ee_b1 = (const float*)d_in[15];
    const float* ee_w2 = (const float*)d_in[16];
    const float* ee_b2 = (const float*)d_in[17];
    const float* msg1_w = (const float*)d_in[18];
    const float* msg1_b = (const float*)d_in[19];
    const float* upd1_w = (const float*)d_in[20];
    const float* upd1_b = (const float*)d_in[21];
    const float* msg2_w = (const float*)d_in[22];
    const float* msg2_b = (const float*)d_in[23];
    const float* upd2_w = (const float*)d_in[24];
    const float* upd2_b = (const float*)d_in[25];
    const float* ec_w1 = (const float*)d_in[26];
    const float* ec_b1 = (const float*)d_in[27];
    const float* ec_w2 = (const float*)d_in[28];
    const float* ec_b2 = (const float*)d_in[29];
    const float* nc_w1 = (const float*)d_in[30];
    const float* nc_b1 = (const float*)d_in[31];
    const float* bn_g = (const float*)d_in[32];
    const float* bn_b = (const float*)d_in[33];
    const float* bn_m = (const float*)d_in[34];
    const float* bn_v = (const float*)d_in[35];
    const float* nc_w2 = (const float*)d_in[36];
    const float* nc_b2 = (const float*)d_in[37];

    float* out_node = (float*)d_out;              // [N_NODES]
    float* out_edge = (float*)d_out + N_NODES;    // [N_EDGES]

    // workspace layout (floats)
    float* ws0 = (float*)d_ws;
    float* eap = ws0;                            // E*32 packed f16, DST-SLOT order
    float* Pp = eap + (long)N_EDGES * 32;        // N*64 packed (einfo alias)
    float* s = Pp + (long)N_NODES * 64;          // N*128 fp32
    float* h1 = s + (long)N_NODES * 128;         // N*128 fp32
    float* ne = h1 + (long)N_NODES * 128;        // N*64 fp32
    float* nSDp = ne + (long)N_NODES * 64;       // N*64 packed (src 32 ++ dst 32)
    float* feat8 = nSDp + (long)N_NODES * 64;    // N*8
    float* Ctp = feat8 + (long)N_NODES * 8;      // 64*32
    float* ncw1t = Ctp + 64 * 32;                // 64*72
    int* tsmax = (int*)(ncw1t + 64 * 72);        // 1
    int* degi = tsmax + 1;                       // N  (dst degree)
    int* degs = degi + N_NODES;                  // N  (src degree; reused as cur_s)
    int* row_d = degs + N_NODES;                 // N+1
    int* row_s = row_d + N_NODES + 1;            // N+1
    int* cur_d = row_s + N_NODES + 1;            // N
    int* eid = cur_d + N_NODES;                  // E (dst-sorted)
    int* eid_src = eid + N_EDGES;                // E (src-sorted)
    int* islot = eid_src + N_EDGES;              // E (edge -> dst slot)
    int* partials = islot + N_EDGES;             // 512
    float* W12tp = (float*)(partials + 512);     // 8960 words
    float* Wm1tp = W12tp + 8960;                 // 4608
    float* Wm2tp = Wm1tp + 4608;                 // 4608
    float* Wpre1 = Wm2tp + 4608;                 // 9216
    float* Wupd1 = Wpre1 + 9216;                 // 18432
    float* Wpre2 = Wupd1 + 18432;                // 9216
    float* Wupd2 = Wpre2 + 9216;                 // 9216
    float* Wec = Wupd2 + 9216;                   // 4608
    float4* einfo = (float4*)Pp;                 // aliases Pp (dead after 2nd msg_seg)

    const int EB = (N_EDGES + 255) / 256;
    const int NB = (N_NODES + 255) / 256;        // 196
    const int NB2 = (N_NODES + 63) / 64;         // 782
    const int MB = (N_EDGES + 63) / 64;          // 7813
    const int EEB = (N_EDGES + 64 * EE_TILES - 1) / (64 * EE_TILES);  // 1954

    // ---- init ----
    hipMemsetAsync(tsmax, 0, (size_t)(1 + 2 * N_NODES) * 4, stream);  // tsmax+degi+degs
    hipMemsetAsync(s, 0, (size_t)N_NODES * 128 * 4, stream);

    // ---- dual-CSR build (cur_s aliases degs; degs dead after scan) ----
    k_deg_count<<<EB, 256, 0, stream>>>(eidx, degi, degs);
    k_block_sums2<<<dim3(NB, 2), 256, 0, stream>>>(degi, degs, partials, N_NODES);
    k_scan_partials2<<<2, 256, 0, stream>>>(partials, NB);
    k_scan_final2<<<dim3(NB, 2), 256, 0, stream>>>(degi, degs, partials,
                                                   row_d, row_s, cur_d, degs, N_NODES);
    k_fill_slots<<<EB, 256, 0, stream>>>(eidx, cur_d, degs, eid, eid_src, islot);

    // ---- weight prep (all LDS-ready f16 images) ----
    k_prep_weights<<<295, 256, 0, stream>>>(ec_w1 + 128 * 64, Ctp, nc_w1, ncw1t,
                                            ee_w1, ee_w2, W12tp,
                                            msg1_w + 128 * 128, Wm1tp,
                                            msg2_w + 128 * 128, Wm2tp,
                                            msg1_w, Wpre1, upd1_w, Wupd1,
                                            msg2_w, Wpre2, upd2_w, Wupd2,
                                            ec_w1, Wec);

    // ---- edge encoder (MFMA; writes ea in dst-slot order) ----
    k_edge_enc_mfma<<<EEB, 256, 0, stream>>>(la, tse, bp, tt, cr, tsp, tg, r7, r30,
                                             tx_emb, bank_emb, W12tp, ee_b1, ee_b2,
                                             islot, eap, N_EDGES);

    // ---- SAGE layer 1 ----
    k_node_gemm_mfma<128, 0, 128, false, false, true><<<NB2, 256, 0, stream>>>(
        x, 128, nullptr, 0, nullptr, Wpre1, nullptr, Pp, 64, N_NODES);
    k_msg_seg_mfma<<<MB, 256, 0, stream>>>(Pp, eap, Wm1tp, msg1_b, src, dst, eid, s, N_EDGES);
    k_node_gemm_mfma<128, 128, 128, true, true, false><<<NB2, 256, 0, stream>>>(
        x, 128, s, 128, degi, Wupd1, upd1_b, h1, 128, N_NODES);

    // ---- SAGE layer 2 ----
    k_node_gemm_mfma<128, 0, 128, false, false, true><<<NB2, 256, 0, stream>>>(
        h1, 128, nullptr, 0, nullptr, Wpre2, nullptr, Pp, 64, N_NODES);
    hipMemsetAsync(s, 0, (size_t)N_NODES * 128 * 4, stream);
    k_msg_seg_mfma<<<MB, 256, 0, stream>>>(Pp, eap, Wm2tp, msg2_b, src, dst, eid, s, N_EDGES);
    k_node_gemm_mfma<128, 128, 64, true, true, false><<<NB2, 256, 0, stream>>>(
        h1, 128, s, 128, degi, Wupd2, upd2_b, ne, 64, N_NODES);
    // Pp dead from here -> einfo alias safe

    // ---- edge classifier prep: ne @ [W_src || W_dst] -> nSDp, one MFMA dispatch ----
    k_node_gemm_mfma<64, 0, 128, false, false, true><<<NB2, 256, 0, stream>>>(
        ne, 64, nullptr, 0, nullptr, Wec, nullptr, nSDp, 64, N_NODES);

    // ---- edge classifier (MFMA + early gathers; ea via islot) ----
    k_tsmax<<<256, 256, 0, stream>>>(uts, tsmax);
    k_edge_cls_mfma<<<MB, 256, 0, stream>>>(nSDp, eap, islot, Ctp, ec_b1, ec_w2, ec_b2,
                                            src, dst, uts, tsmax, out_edge, einfo, N_EDGES);

    // ---- node aggregation (dual CSR) ----
    k_node_agg<<<NB, 256, 0, stream>>>(einfo, row_d, eid, row_s, eid_src, feat8);

    // ---- node classifier ----
    k_node_cls<<<NB, 256, 0, stream>>>(ne, feat8, ncw1t, nc_b1, bn_g, bn_b, bn_m, bn_v,
                                       nc_w2, nc_b2, out_node);
}

// Round 10
// 677.833 us; speedup vs baseline: 1.0674x; 1.0645x over previous
//
#include <hip/hip_runtime.h>
#include <math.h>

#define N_NODES 50000
#define N_EDGES 500000

// ---------- f16 pair helpers ----------
typedef _Float16 h2_t __attribute__((ext_vector_type(2)));
__device__ inline float pk(float a, float b) {
    h2_t h; h[0] = (_Float16)a; h[1] = (_Float16)b;
    float r; __builtin_memcpy(&r, &h, 4); return r;
}
__device__ inline float2 upk(float p) {
    h2_t h; __builtin_memcpy(&h, &p, 4);
    return make_float2((float)h[0], (float)h[1]);
}

// ---------- MFMA types ----------
typedef _Float16 f16x8 __attribute__((ext_vector_type(8)));
typedef float f32x4 __attribute__((ext_vector_type(4)));

// =================== dual-CSR build (dst-sorted eid + src-sorted eid_src) ==============
__global__ void k_deg_count(const int* __restrict__ eidx,
                            int* __restrict__ degi, int* __restrict__ degs) {
    int i = blockIdx.x * blockDim.x + threadIdx.x;
    if (i < N_EDGES) {
        atomicAdd(degi + eidx[N_EDGES + i], 1);  // dst
        atomicAdd(degs + eidx[i], 1);            // src
    }
}

__global__ void k_block_sums2(const int* __restrict__ degi, const int* __restrict__ degs,
                              int* __restrict__ partials, int n) {
    const int* deg = blockIdx.y ? degs : degi;
    int* part = partials + blockIdx.y * 256;
    __shared__ int sm[256];
    int i = blockIdx.x * 256 + threadIdx.x;
    sm[threadIdx.x] = (i < n) ? deg[i] : 0;
    __syncthreads();
    for (int s = 128; s > 0; s >>= 1) {
        if (threadIdx.x < s) sm[threadIdx.x] += sm[threadIdx.x + s];
        __syncthreads();
    }
    if (threadIdx.x == 0) part[blockIdx.x] = sm[0];
}

__global__ void k_scan_partials2(int* partials, int nb) {
    int* part = partials + blockIdx.x * 256;
    __shared__ int sm[256];
    int v = (threadIdx.x < nb) ? part[threadIdx.x] : 0;
    sm[threadIdx.x] = v;
    __syncthreads();
    for (int off = 1; off < 256; off <<= 1) {
        int t = (threadIdx.x >= off) ? sm[threadIdx.x - off] : 0;
        __syncthreads();
        sm[threadIdx.x] += t;
        __syncthreads();
    }
    if (threadIdx.x < nb) part[threadIdx.x] = sm[threadIdx.x] - v;
}

// also writes the cursor copies. NOTE: cur may alias deg (read-before-write per
// thread, no cross-index access) — the launcher passes cur_s == degs.
__global__ void k_scan_final2(const int* __restrict__ degi, const int* __restrict__ degs,
                              const int* __restrict__ partials,
                              int* __restrict__ row_d, int* __restrict__ row_s,
                              int* __restrict__ cur_d, int* __restrict__ cur_s, int n) {
    const int* deg = blockIdx.y ? degs : degi;
    const int* part = partials + blockIdx.y * 256;
    int* row = blockIdx.y ? row_s : row_d;
    int* cur = blockIdx.y ? cur_s : cur_d;
    __shared__ int sm[256];
    int i = blockIdx.x * 256 + threadIdx.x;
    int v = (i < n) ? deg[i] : 0;
    sm[threadIdx.x] = v;
    __syncthreads();
    for (int off = 1; off < 256; off <<= 1) {
        int t = (threadIdx.x >= off) ? sm[threadIdx.x - off] : 0;
        __syncthreads();
        sm[threadIdx.x] += t;
        __syncthreads();
    }
    if (i < n) {
        int rv = part[blockIdx.x] + sm[threadIdx.x] - v;
        row[i] = rv; cur[i] = rv;
    }
    if (i == n - 1) row[n] = part[blockIdx.x] + sm[threadIdx.x];
}

// also writes islot (edge -> dst-slot), coalesced.
__global__ void k_fill_slots(const int* __restrict__ eidx,
                             int* __restrict__ cur_d, int* __restrict__ cur_s,
                             int* __restrict__ eid, int* __restrict__ eid_src,
                             int* __restrict__ islot) {
    int i = blockIdx.x * blockDim.x + threadIdx.x;
    if (i < N_EDGES) {
        int pd = atomicAdd(cur_d + eidx[N_EDGES + i], 1);
        eid[pd] = i;
        islot[i] = pd;
        int ps = atomicAdd(cur_s + eidx[i], 1);
        eid_src[ps] = i;
    }
}

// ---------------- weight prep: ALL LDS-ready f16 images prepacked ----------------------
// Image layout per 64-K chunk: [c: JC][36 words] (32 kp pairs + 4 pad) — exactly the
// LDS layout, so per-block staging is a linear conflict-free float4 copy.
__device__ inline float pack_img(const float* __restrict__ W, int ldw, int JC, int u) {
    int per = 36 * JC;
    int chunk = u / per, r = u - chunk * per;
    int c = r / 36, w = r - c * 36;
    if (w >= 32) return 0.f;
    return pk(W[(long)(chunk * 64 + 2 * w) * ldw + c],
              W[(long)(chunk * 64 + 2 * w + 1) * ldw + c]);
}

__global__ void k_prep_weights(
    const float* __restrict__ C /*ec rows128..191*/, float* __restrict__ Ctp,
    const float* __restrict__ nc_w1, float* __restrict__ ncw1t,
    const float* __restrict__ ee_w1, const float* __restrict__ ee_w2, float* __restrict__ W12tp,
    const float* __restrict__ m1w, float* __restrict__ Wm1tp,
    const float* __restrict__ m2w, float* __restrict__ Wm2tp,
    const float* __restrict__ msg1_w, float* __restrict__ Wpre1,
    const float* __restrict__ upd1_w, float* __restrict__ Wupd1,
    const float* __restrict__ msg2_w, float* __restrict__ Wpre2,
    const float* __restrict__ upd2_w, float* __restrict__ Wupd2,
    const float* __restrict__ ec_w1, float* __restrict__ Wec) {
    int i = blockIdx.x * 256 + threadIdx.x;
    if (i < 2048) {
        int j = i >> 5, k2 = i & 31;
        Ctp[i] = pk(C[(2 * k2) * 64 + j], C[(2 * k2 + 1) * 64 + j]);
        return;
    }
    int t = i - 2048;
    if (t < 72 * 64) {
        int k = t / 64, j = t - k * 64;
        ncw1t[j * 72 + k] = nc_w1[k * 64 + j];
        return;
    }
    int u = t - 72 * 64;
    if (u < 4608) {                        // edge-enc W1t [128][36]
        int c = u / 36, w = u % 36;
        float v = 0.f;
        if (w < 32) {
            float a = (2 * w < 38) ? ee_w1[(2 * w) * 128 + c] : 0.f;
            float b = (2 * w + 1 < 38) ? ee_w1[(2 * w + 1) * 128 + c] : 0.f;
            v = pk(a, b);
        }
        W12tp[u] = v;
        return;
    }
    u -= 4608;
    if (u < 4352) {                        // edge-enc W2t [64][68]
        int c = u / 68, w = u % 68;
        float v = 0.f;
        if (w < 64) v = pk(ee_w2[(2 * w) * 64 + c], ee_w2[(2 * w + 1) * 64 + c]);
        W12tp[4608 + u] = v;
        return;
    }
    u -= 4352;
    if (u < 4608) { Wm1tp[u] = pack_img(m1w, 128, 128, u); return; }
    u -= 4608;
    if (u < 4608) { Wm2tp[u] = pack_img(m2w, 128, 128, u); return; }
    u -= 4608;
    if (u < 9216) { Wpre1[u] = pack_img(msg1_w, 128, 128, u); return; }
    u -= 9216;
    if (u < 18432) { Wupd1[u] = pack_img(upd1_w, 128, 128, u); return; }
    u -= 18432;
    if (u < 9216) { Wpre2[u] = pack_img(msg2_w, 128, 128, u); return; }
    u -= 9216;
    if (u < 9216) { Wupd2[u] = pack_img(upd2_w, 64, 64, u); return; }
    u -= 9216;
    if (u < 4608) {                        // Wec: [c:128][36]; c<64 -> src half, c>=64 -> dst half
        int c = u / 36, w = u % 36;
        float v = 0.f;
        if (w < 32) {
            if (c < 64) v = pk(ec_w1[(2 * w) * 64 + c], ec_w1[(2 * w + 1) * 64 + c]);
            else v = pk(ec_w1[(64 + 2 * w) * 64 + (c - 64)], ec_w1[(64 + 2 * w + 1) * 64 + (c - 64)]);
        }
        Wec[u] = v;
    }
}

// ---------------- edge encoder, MFMA + persistent weights + 4 tiles/block --------------
// Output written in DST-SLOT order: eap[islot[e]] (scattered 128B rows) so that both
// msg_seg dispatches read ea as a linear stream; edge_cls absorbs the one gather.
#define EE_TILES 4
#define EE_W1O 0
#define EE_W2O 9216
#define EE_TO 17920
#define EE_SMH2 26624

__global__ __launch_bounds__(256) void k_edge_enc_mfma(
    const float* __restrict__ la, const float* __restrict__ tse,
    const int* __restrict__ bp, const int* __restrict__ tt,
    const float* __restrict__ cr, const float* __restrict__ tsp,
    const float* __restrict__ tg, const float* __restrict__ r7,
    const float* __restrict__ r30,
    const float* __restrict__ tx_emb, const float* __restrict__ bank_emb,
    const float* __restrict__ W12tp, const float* __restrict__ eb1,
    const float* __restrict__ eb2, const int* __restrict__ islot,
    float* __restrict__ eap /*E x 32, slot-ordered*/, int n_edges) {
    __shared__ __align__(16) _Float16 sm[EE_SMH2];
    __shared__ int isl_s[64];
    float* smf = (float*)sm;  // word view
    int tid = threadIdx.x;

    // ---- stage W1t+W2t once: 2240 float4s, linear (conflict-free) ----
    {
        const float4* Wg = (const float4*)W12tp;
        float4* Wl = (float4*)sm;
#pragma unroll
        for (int i = 0; i < 9; i++) {
            int idx = tid + 256 * i;
            if (idx < 2240) Wl[idx] = Wg[idx];
        }
    }

    int lane = tid & 63;
    int wv = tid >> 6;
    int lrow = lane & 15;
    int lk = (lane >> 4) << 3;
    int rbase = (lane >> 4) << 2;

#pragma unroll 1
    for (int tile = 0; tile < EE_TILES; tile++) {
        int t0 = (blockIdx.x * EE_TILES + tile) * 64;
        if (t0 >= n_edges) break;
        __syncthreads();  // weights staged / prev tile copy-out done

        // ---- feature build into F @ word 8960, stride 36 words; stage isl ----
        if (tid < 64) isl_s[tid] = (t0 + tid < n_edges) ? islot[t0 + tid] : 0;
        {
            int el = tid & 63, g = tid >> 6;
            int e = t0 + el;
            bool ok = e < n_edges;
            float* Fr = smf + 8960 + el * 36;
            if (g == 0) {
                Fr[0] = ok ? pk(la[e], cr[e]) : 0.f;
                Fr[1] = ok ? pk(tsp[e], tg[e]) : 0.f;
                Fr[2] = ok ? pk(r7[e], r30[e]) : 0.f;
#pragma unroll
                for (int z = 19; z < 32; z++) Fr[z] = 0.f;  // K pad -> zero
            } else if (g == 1) {
                float4 a = make_float4(0, 0, 0, 0), b = a;
                if (ok) { a = ((const float4*)(tse + (long)e * 8))[0];
                          b = ((const float4*)(tse + (long)e * 8))[1]; }
                Fr[3] = pk(a.x, a.y); Fr[4] = pk(a.z, a.w);
                Fr[5] = pk(b.x, b.y); Fr[6] = pk(b.z, b.w);
            } else if (g == 2) {
                float4 a = make_float4(0, 0, 0, 0), b = a;
                if (ok) { int txi = tt[e];
                          a = ((const float4*)(tx_emb + (long)txi * 8))[0];
                          b = ((const float4*)(tx_emb + (long)txi * 8))[1]; }
                Fr[7] = pk(a.x, a.y); Fr[8] = pk(a.z, a.w);
                Fr[9] = pk(b.x, b.y); Fr[10] = pk(b.z, b.w);
            } else {
                float4 a = make_float4(0, 0, 0, 0), b = a, c = a, d = a;
                if (ok) {
                    int bk0 = bp[e * 2 + 0], bk1 = bp[e * 2 + 1];
                    a = ((const float4*)(bank_emb + (long)bk0 * 8))[0];
                    b = ((const float4*)(bank_emb + (long)bk0 * 8))[1];
                    c = ((const float4*)(bank_emb + (long)bk1 * 8))[0];
                    d = ((const float4*)(bank_emb + (long)bk1 * 8))[1];
                }
                Fr[11] = pk(a.x, a.y); Fr[12] = pk(a.z, a.w);
                Fr[13] = pk(b.x, b.y); Fr[14] = pk(b.z, b.w);
                Fr[15] = pk(c.x, c.y); Fr[16] = pk(c.z, c.w);
                Fr[17] = pk(d.x, d.y); Fr[18] = pk(d.z, d.w);
            }
        }
        __syncthreads();

        // ---- GEMM1 ----
        f16x8 a0 = *(const f16x8*)(sm + EE_TO + (wv * 16 + lrow) * 72 + lk);
        f16x8 a1 = *(const f16x8*)(sm + EE_TO + (wv * 16 + lrow) * 72 + 32 + lk);
        f32x4 acc[8];
#pragma unroll
        for (int ct = 0; ct < 8; ct++) {
            const _Float16* wb = sm + EE_W1O + (ct * 16 + lrow) * 72 + lk;
            f16x8 b0 = *(const f16x8*)(wb);
            f16x8 b1 = *(const f16x8*)(wb + 32);
            f32x4 z = {0.f, 0.f, 0.f, 0.f};
            acc[ct] = __builtin_amdgcn_mfma_f32_16x16x32_f16(a0, b0, z, 0, 0, 0);
            acc[ct] = __builtin_amdgcn_mfma_f32_16x16x32_f16(a1, b1, acc[ct], 0, 0, 0);
        }
        __syncthreads();  // F consumed -> overlay with H

        // ---- bias + relu -> H (f16, stride 136 hw) ----
#pragma unroll
        for (int ct = 0; ct < 8; ct++) {
            int col = ct * 16 + lrow;
            float bias = eb1[col];
#pragma unroll
            for (int r = 0; r < 4; r++) {
                int row = wv * 16 + rbase + r;
                sm[EE_TO + row * 136 + col] = (_Float16)fmaxf(acc[ct][r] + bias, 0.f);
            }
        }
        __syncthreads();

        // ---- GEMM2 ----
        f32x4 acc2[4];
#pragma unroll
        for (int ct = 0; ct < 4; ct++) { f32x4 z = {0.f, 0.f, 0.f, 0.f}; acc2[ct] = z; }
#pragma unroll
        for (int ks = 0; ks < 4; ks++) {
            f16x8 av = *(const f16x8*)(sm + EE_TO + (wv * 16 + lrow) * 136 + ks * 32 + lk);
#pragma unroll
            for (int ct = 0; ct < 4; ct++) {
                f16x8 bv = *(const f16x8*)(sm + EE_W2O + (ct * 16 + lrow) * 136 + ks * 32 + lk);
                acc2[ct] = __builtin_amdgcn_mfma_f32_16x16x32_f16(av, bv, acc2[ct], 0, 0, 0);
            }
        }
        __syncthreads();  // H consumed -> overlay with O

        // ---- bias -> O (f16, stride 72 hw = 36 words, pair order == eap layout) ----
#pragma unroll
        for (int ct = 0; ct < 4; ct++) {
            int col = ct * 16 + lrow;
            float bias = eb2[col];
#pragma unroll
            for (int r = 0; r < 4; r++) {
                int row = wv * 16 + rbase + r;
                sm[EE_TO + row * 72 + col] = (_Float16)(acc2[ct][r] + bias);
            }
        }
        __syncthreads();

        // ---- copy-out to slot position: float4 (G13 — wide stores) ----
#pragma unroll
        for (int rep = 0; rep < 2; rep++) {
            int idx = rep * 256 + tid;     // 0..511 float4s
            int el = idx >> 3, c4 = idx & 7;
            int e = t0 + el;
            if (e < n_edges) {
                float4 v = *(const float4*)(smf + 8960 + el * 36 + c4 * 4);
                *((float4*)(eap + (long)isl_s[el] * 32 + c4 * 4)) = v;
            }
        }
    }
}

// ---------------- node-level GEMM via MFMA, prepacked W images -------------------------
template <int K1, int K2, int JC, bool RELU, bool DIV2, bool PACKOUT>
__global__ __launch_bounds__(256) void k_node_gemm_mfma(
    const float* __restrict__ in1, int ld1,
    const float* __restrict__ in2, int ld2,
    const int* __restrict__ degv,
    const float* __restrict__ Wimg,   // per-chunk [JC][36] words, prepacked
    const float* __restrict__ bias,
    float* __restrict__ out, int ldo, int nrows) {
    constexpr int NC = (K1 + K2) / 64;
    constexpr int NCT = JC / 16;
    constexpr int AB_HW = 4608 + JC * 72;
    constexpr int OUT_HW = PACKOUT ? 64 * (JC + 8) : 64 * (JC + 4) * 2;
    constexpr int SM_HW = AB_HW > OUT_HW ? AB_HW : OUT_HW;
    __shared__ __align__(16) _Float16 sm[SM_HW];
    float* smw = (float*)sm;  // u32 word view
    int tid = threadIdx.x;
    int t0 = blockIdx.x * 64;

    int lane = tid & 63, wv = tid >> 6;
    int lrow = lane & 15, lk = (lane >> 4) << 3, rbase = (lane >> 4) << 2;

    f32x4 acc[NCT];
#pragma unroll
    for (int ct = 0; ct < NCT; ct++) {
        float b = bias ? bias[ct * 16 + lrow] : 0.f;
        f32x4 v = {b, b, b, b};
        acc[ct] = v;
    }

#pragma unroll 1
    for (int kc = 0; kc < NC; kc++) {
        __syncthreads();
        // ---- stage A chunk (coalesced float4, f16 into [64][72]) ----
        {
            const float* src = (kc * 64 < K1) ? in1 : in2;
            int ld = (kc * 64 < K1) ? ld1 : ld2;
            int ko = (kc * 64 < K1) ? kc * 64 : kc * 64 - K1;
            bool isdiv = DIV2 && (kc * 64 >= K1);
#pragma unroll
            for (int i = 0; i < 4; i++) {
                int f = tid + 256 * i;         // float4 id 0..1023
                int row = f >> 4, c4 = f & 15;
                int grow = t0 + row;
                float4 v = make_float4(0, 0, 0, 0);
                if (grow < nrows) {
                    v = *(const float4*)(src + (long)grow * ld + ko + c4 * 4);
                    if (isdiv) {
                        float dv = 1.f / ((float)degv[grow] + 1e-6f);
                        v.x *= dv; v.y *= dv; v.z *= dv; v.w *= dv;
                    }
                }
                float2 o; o.x = pk(v.x, v.y); o.y = pk(v.z, v.w);
                *((float2*)(sm + row * 72 + c4 * 4)) = o;
            }
        }
        // ---- stage W chunk: linear float4 copy from prepacked image ----
        {
            const float4* Wg = (const float4*)(Wimg + (long)kc * (36 * JC));
            float4* Wl = (float4*)(smw + 2304);
            constexpr int NF4 = 36 * JC / 4;
            constexpr int NI = (NF4 + 255) / 256;
#pragma unroll
            for (int i = 0; i < NI; i++) {
                int idx = tid + 256 * i;
                if (idx < NF4) Wl[idx] = Wg[idx];
            }
        }
        __syncthreads();
        // ---- MFMA: 2 k-steps x NCT col-tiles ----
        f16x8 a0 = *(const f16x8*)(sm + (wv * 16 + lrow) * 72 + lk);
        f16x8 a1 = *(const f16x8*)(sm + (wv * 16 + lrow) * 72 + 32 + lk);
#pragma unroll
        for (int ct = 0; ct < NCT; ct++) {
            const _Float16* wb = sm + 4608 + (ct * 16 + lrow) * 72 + lk;
            f16x8 b0 = *(const f16x8*)(wb);
            f16x8 b1 = *(const f16x8*)(wb + 32);
            acc[ct] = __builtin_amdgcn_mfma_f32_16x16x32_f16(a0, b0, acc[ct], 0, 0, 0);
            acc[ct] = __builtin_amdgcn_mfma_f32_16x16x32_f16(a1, b1, acc[ct], 0, 0, 0);
        }
    }
    __syncthreads();

    if constexpr (PACKOUT) {
#pragma unroll
        for (int ct = 0; ct < NCT; ct++) {
            int col = ct * 16 + lrow;
#pragma unroll
            for (int r = 0; r < 4; r++) {
                float v = acc[ct][r];
                if (RELU) v = fmaxf(v, 0.f);
                sm[(wv * 16 + rbase + r) * (JC + 8) + col] = (_Float16)v;
            }
        }
        __syncthreads();
        constexpr int F4R = JC / 8;
        constexpr int NO = 64 * F4R / 256;
#pragma unroll
        for (int i = 0; i < NO; i++) {
            int idx = tid + 256 * i;
            int row = idx / F4R, c4 = idx % F4R;
            int grow = t0 + row;
            if (grow < nrows) {
                float4 v = *(const float4*)(sm + row * (JC + 8) + c4 * 8);
                *((float4*)(out + (long)grow * ldo + c4 * 4)) = v;
            }
        }
    } else {
        float* Of = smw;  // f32 [64][JC+4]
#pragma unroll
        for (int ct = 0; ct < NCT; ct++) {
            int col = ct * 16 + lrow;
#pragma unroll
            for (int r = 0; r < 4; r++) {
                float v = acc[ct][r];
                if (RELU) v = fmaxf(v, 0.f);
                Of[(wv * 16 + rbase + r) * (JC + 4) + col] = v;
            }
        }
        __syncthreads();
        constexpr int F4R = JC / 4;
        constexpr int NO = 64 * F4R / 256;
#pragma unroll
        for (int i = 0; i < NO; i++) {
            int idx = tid + 256 * i;
            int row = idx / F4R, c4 = idx % F4R;
            int grow = t0 + row;
            if (grow < nrows) {
                float4 v = *(const float4*)(Of + row * (JC + 4) + c4 * 4);
                *((float4*)(out + (long)grow * ldo + c4 * 4)) = v;
            }
        }
    }
}

// ---------------- msg GEMM via MFMA + segmented sum ------------------------------------
// ea slot-ordered -> staging is a LINEAR float4 STREAM (wide loads; G13).
__global__ __launch_bounds__(256) void k_msg_seg_mfma(
    const float* __restrict__ Pp /*N x 64 packed*/, const float* __restrict__ eap,
    const float* __restrict__ Wt_g /*4608 words*/, const float* __restrict__ bias,
    const int* __restrict__ src, const int* __restrict__ dst,
    const int* __restrict__ eid,
    float* __restrict__ s, int n_edges) {
    __shared__ __align__(16) float smem[8320];   // Mt f32[128][65]
    _Float16* smh = (_Float16*)smem;
    float* Mt = smem;
    __shared__ int sn_s[64];
    __shared__ int nid_s[64];
    __shared__ int bound_s[2];
    int tid = threadIdx.x;
    int t0 = blockIdx.x * 64;

    if (tid < 64) {
        int slot = t0 + tid;
        int e = (slot < n_edges) ? eid[slot] : 0;
        sn_s[tid] = src[e];
        nid_s[tid] = (slot < n_edges) ? dst[e] : -1;
    }
    if (tid == 64) bound_s[0] = (t0 > 0) ? dst[eid[t0 - 1]] : -1;
    if (tid == 65) bound_s[1] = (t0 + 64 < n_edges) ? dst[eid[t0 + 64]] : -1;

    // ---- stage W^T: linear float4 copy (conflict-free, coalesced) ----
    {
        const float4* Wg = (const float4*)Wt_g;
        float4* Wl = (float4*)smem;
#pragma unroll
        for (int i = 0; i < 5; i++) {
            int idx = tid + 256 * i;
            if (idx < 1152) Wl[idx] = Wg[idx];
        }
    }
    __syncthreads();

    int lane = tid & 63;
    int wv = tid >> 6;
    int lrow = lane & 15;
    int lk = (lane >> 4) << 3;
    int rbase = (lane >> 4) << 2;

    // ---- early P gathers + bias (consumed after MFMA) ----
    int srcs[4];
#pragma unroll
    for (int ct = 0; ct < 4; ct++) srcs[ct] = sn_s[ct * 16 + lrow];
    float2 pvr[2][4];
    float4 bv4[2];
#pragma unroll
    for (int rt = 0; rt < 2; rt++) {
        int chb = wv * 32 + rt * 16 + rbase;
        bv4[rt] = *(const float4*)(bias + chb);
#pragma unroll
        for (int ct = 0; ct < 4; ct++)
            pvr[rt][ct] = *(const float2*)(Pp + (long)srcs[ct] * 64 + (chb >> 1));
    }

    // ---- stage ea rows: LINEAR float4 stream ----
#pragma unroll
    for (int i = 0; i < 2; i++) {
        int idx = tid + 256 * i;        // 0..511 float4s
        int el = idx >> 3, c = idx & 7;
        int e2 = t0 + el;
        float4 v = make_float4(0, 0, 0, 0);
        if (e2 < n_edges) v = *((const float4*)(eap + (long)e2 * 32 + c * 4));
        *((float4*)(smem + 4608 + el * 36 + c * 4)) = v;
    }
    __syncthreads();

    // ---- MFMA: wave wv owns channels wv*32..+31 (2 row-tiles) x 4 edge col-tiles ----
    f32x4 acc[2][4];
#pragma unroll
    for (int rt = 0; rt < 2; rt++)
#pragma unroll
        for (int ct = 0; ct < 4; ct++) { f32x4 z = {0.f, 0.f, 0.f, 0.f}; acc[rt][ct] = z; }
#pragma unroll
    for (int ks = 0; ks < 2; ks++) {
        f16x8 bfr[4];
#pragma unroll
        for (int ct = 0; ct < 4; ct++)
            bfr[ct] = *(const f16x8*)(smh + 9216 + (ct * 16 + lrow) * 72 + ks * 32 + lk);
#pragma unroll
        for (int rt = 0; rt < 2; rt++) {
            f16x8 av = *(const f16x8*)(smh + (wv * 32 + rt * 16 + lrow) * 72 + ks * 32 + lk);
#pragma unroll
            for (int ct = 0; ct < 4; ct++)
                acc[rt][ct] = __builtin_amdgcn_mfma_f32_16x16x32_f16(av, bfr[ct], acc[rt][ct], 0, 0, 0);
        }
    }
    __syncthreads();  // A/B consumed -> overlay with Mt

    // ---- Mt = relu(acc + bias + P[src]) ----
#pragma unroll
    for (int rt = 0; rt < 2; rt++) {
        int chb = wv * 32 + rt * 16 + rbase;
        float4 bv = bv4[rt];
#pragma unroll
        for (int ct = 0; ct < 4; ct++) {
            int edge = ct * 16 + lrow;
            float2 pa = upk(pvr[rt][ct].x), pb = upk(pvr[rt][ct].y);
            f32x4 a = acc[rt][ct];
            Mt[(chb + 0) * 65 + edge] = fmaxf(a[0] + pa.x + bv.x, 0.f);
            Mt[(chb + 1) * 65 + edge] = fmaxf(a[1] + pa.y + bv.y, 0.f);
            Mt[(chb + 2) * 65 + edge] = fmaxf(a[2] + pb.x + bv.z, 0.f);
            Mt[(chb + 3) * 65 + edge] = fmaxf(a[3] + pb.y + bv.w, 0.f);
        }
    }
    __syncthreads();

    // ---- segmented sum: 256 threads = 128 channels x 2 row-halves ----
    {
        int c = tid & 127;
        int h = tid >> 7;
        int rows = min(64, n_edges - t0);
        int r0 = h * 32;
        int r1 = min(rows, r0 + 32);
        if (r0 < r1) {
            int prev_n = h ? nid_s[31] : bound_s[0];
            int next_n = h ? bound_s[1] : ((rows > 32) ? nid_s[32] : bound_s[1]);
            int cur = nid_s[r0];
            int seg_start = r0;
            float run = 0.f;
            for (int r = r0; r < r1; r++) {
                int nd = nid_s[r];
                if (nd != cur) {
                    if (seg_start == r0 && cur == prev_n) atomicAdd(s + (long)cur * 128 + c, run);
                    else s[(long)cur * 128 + c] = run;
                    cur = nd; seg_start = r; run = 0.f;
                }
                run += Mt[c * 65 + r];
            }
            if ((seg_start == r0 && cur == prev_n) || cur == next_n)
                atomicAdd(s + (long)cur * 128 + c, run);
            else s[(long)cur * 128 + c] = run;
        }
    }
}

// ---------------- edge classifier, MFMA + early gathers; ea gathered via islot ---------
__global__ __launch_bounds__(256) void k_edge_cls_mfma(
    const float* __restrict__ nSDp /*N x 64 (32 src-pk + 32 dst-pk)*/,
    const float* __restrict__ eap /*slot-ordered*/, const int* __restrict__ islot,
    const float* __restrict__ Ctp /*[64 j][32 k2] packed*/,
    const float* __restrict__ b1, const float* __restrict__ w2, const float* __restrict__ b2,
    const int* __restrict__ src, const int* __restrict__ dst,
    const int* __restrict__ uts, const int* __restrict__ tsmax,
    float* __restrict__ logits_out, float4* __restrict__ einfo, int n_edges) {
    __shared__ __align__(16) _Float16 smAB[9216];
    __shared__ int sn_s[64], dn_s[64], isl_s[64];
    __shared__ float b1_s[64], w2_s[64], logit_s[64];
    float* Of = (float*)smAB;  // overlay after MFMA
    float* smABw = (float*)smAB;
    int tid = threadIdx.x;
    int t0 = blockIdx.x * 64;

    if (tid < 64) {
        int e = min(t0 + tid, n_edges - 1);
        sn_s[tid] = src[e];
        dn_s[tid] = dst[e];
        isl_s[tid] = islot[e];
    } else if (tid < 128) {
        b1_s[tid - 64] = b1[tid - 64];
    } else if (tid < 192) {
        w2_s[tid - 128] = w2[tid - 128];
    }
    __syncthreads();

    // ---- early gathers: 4 lanes per edge, 32B each ----
    int el = tid >> 2, q = tid & 3;
    const float4* Sp = (const float4*)(nSDp + (long)sn_s[el] * 64) + q * 2;
    float4 sA = Sp[0], sB = Sp[1];
    const float4* Dp = (const float4*)(nSDp + (long)dn_s[el] * 64 + 32) + q * 2;
    float4 dA = Dp[0], dB = Dp[1];

    // ---- stage A (ea rows via islot, float4 8 lanes/row) and B (Ct, float4) ----
#pragma unroll
    for (int i = 0; i < 2; i++) {
        int idx = tid + 256 * i;        // 0..511 float4s
        int ael = idx >> 3, c = idx & 7;
        int e2 = t0 + ael;
        float4 v = make_float4(0, 0, 0, 0);
        if (e2 < n_edges) v = *((const float4*)(eap + (long)isl_s[ael] * 32 + c * 4));
        *((float4*)(smABw + ael * 36 + c * 4)) = v;
    }
#pragma unroll
    for (int i = 0; i < 2; i++) {
        int idx = tid + 256 * i;        // 0..511 float4s
        int j = idx >> 3, c = idx & 7;
        float4 v = ((const float4*)Ctp)[j * 8 + c];
        *((float4*)(smABw + 2304 + j * 36 + c * 4)) = v;
    }
    __syncthreads();

    int lane = tid & 63;
    int wv = tid >> 6;
    int lrow = lane & 15;
    int lk = (lane >> 4) << 3;
    int rbase = (lane >> 4) << 2;
    f32x4 acc[4];
#pragma unroll
    for (int ct = 0; ct < 4; ct++) { f32x4 z = {0.f, 0.f, 0.f, 0.f}; acc[ct] = z; }
#pragma unroll
    for (int ks = 0; ks < 2; ks++) {
        f16x8 av = *(const f16x8*)(smAB + (wv * 16 + lrow) * 72 + ks * 32 + lk);
#pragma unroll
        for (int ct = 0; ct < 4; ct++) {
            f16x8 bv = *(const f16x8*)(smAB + 4608 + (ct * 16 + lrow) * 72 + ks * 32 + lk);
            acc[ct] = __builtin_amdgcn_mfma_f32_16x16x32_f16(av, bv, acc[ct], 0, 0, 0);
        }
    }
    __syncthreads();  // A/B reads done -> overlay with O

#pragma unroll
    for (int ct = 0; ct < 4; ct++)
#pragma unroll
        for (int r = 0; r < 4; r++)
            Of[(wv * 16 + rbase + r) * 68 + ct * 16 + lrow] = acc[ct][r];
    __syncthreads();

    const float* Orow = Of + el * 68 + q * 16;
    const float* sa = (const float*)&sA;
    const float* sb = (const float*)&sB;
    const float* da = (const float*)&dA;
    const float* db = (const float*)&dB;
    float partial = 0.f;
#pragma unroll
    for (int i = 0; i < 4; i++) {
        float2 su = upk(sa[i]), du = upk(da[i]);
        float v0 = fmaxf(b1_s[q * 16 + 2 * i] + su.x + du.x + Orow[2 * i], 0.f);
        float v1 = fmaxf(b1_s[q * 16 + 2 * i + 1] + su.y + du.y + Orow[2 * i + 1], 0.f);
        partial = fmaf(v0, w2_s[q * 16 + 2 * i], partial);
        partial = fmaf(v1, w2_s[q * 16 + 2 * i + 1], partial);
    }
#pragma unroll
    for (int i = 0; i < 4; i++) {
        float2 su = upk(sb[i]), du = upk(db[i]);
        float v0 = fmaxf(b1_s[q * 16 + 8 + 2 * i] + su.x + du.x + Orow[8 + 2 * i], 0.f);
        float v1 = fmaxf(b1_s[q * 16 + 8 + 2 * i + 1] + su.y + du.y + Orow[8 + 2 * i + 1], 0.f);
        partial = fmaf(v0, w2_s[q * 16 + 8 + 2 * i], partial);
        partial = fmaf(v1, w2_s[q * 16 + 8 + 2 * i + 1], partial);
    }
    partial += __shfl_xor(partial, 1);
    partial += __shfl_xor(partial, 2);
    if (q == 0) logit_s[el] = partial;
    __syncthreads();

    if (tid < 64) {
        int e = t0 + tid;
        if (e < n_edges) {
            float logit = logit_s[tid] + b2[0];
            logits_out[e] = logit;
            float p = 1.f / (1.f + expf(-logit));
            float now = (float)(*tsmax);
            float age = fmaxf(now - (float)uts[e], 0.f);
            float decay = expf(-age / 2592000.f);
            einfo[e] = make_float4(p, decay, age, 0.f);
        }
    }
}

// ---------------- ts max reduction -----------------------------------------------------
__global__ void k_tsmax(const int* __restrict__ ts, int* __restrict__ out) {
    int i = blockIdx.x * blockDim.x + threadIdx.x;
    int stride = gridDim.x * blockDim.x;
    int m = 0;
    for (int t = i; t < N_EDGES; t += stride) m = max(m, ts[t]);
#pragma unroll
    for (int off = 32; off > 0; off >>= 1) m = max(m, __shfl_down(m, off));
    if ((threadIdx.x & 63) == 0) atomicMax(out, m);
}

// ---------------- per-node aggregation over dual CSR (no atomics) ----------------------
__global__ __launch_bounds__(256) void k_node_agg(
    const float4* __restrict__ einfo,
    const int* __restrict__ row_d, const int* __restrict__ eid,
    const int* __restrict__ row_s, const int* __restrict__ eid_src,
    float* __restrict__ feat8) {
    int n = blockIdx.x * blockDim.x + threadIdx.x;
    if (n >= N_NODES) return;
    int d0 = row_d[n], d1 = row_d[n + 1];
    int s0 = row_s[n], s1 = row_s[n + 1];
    float cnt = (float)((d1 - d0) + (s1 - s0));
    float sump = 0.f, maxp = 0.f, sumh = 0.f, sumpd = 0.f, sumd = 0.f;
    float sumh30 = 0.f, maxp30 = 0.f, sump30 = 0.f, suml30 = 0.f, minage = 9999.f;
#pragma unroll 1
    for (int pass = 0; pass < 2; pass++) {
        int a = pass ? s0 : d0, b = pass ? s1 : d1;
        const int* lst = pass ? eid_src : eid;
        for (int idx = a; idx < b; idx++) {
            float4 v = einfo[lst[idx]];
            float p = v.x, decay = v.y, age = v.z;
            float aged = age / 86400.f;
            bool high = p >= 0.7f;
            bool l30 = age <= 2592000.f;
            sump += p;
            maxp = fmaxf(maxp, p);
            sumpd += p * decay;
            sumd += decay;
            if (high) {
                sumh += 1.f;
                minage = fminf(minage, aged);
            }
            if (l30) {
                sump30 += p;
                suml30 += 1.f;
                maxp30 = fmaxf(maxp30, p);
                if (high) sumh30 += 1.f;
            }
        }
    }
    float* f = feat8 + (long)n * 8;
    f[0] = sump / (cnt + 1e-6f);
    f[1] = maxp;
    f[2] = log1pf(sumh);
    f[3] = sumpd / (sumd + 1e-6f);
    f[4] = log1pf(sumh30);
    f[5] = maxp30;
    f[6] = sump30 / (suml30 + 1e-6f);
    f[7] = log1pf(fminf(fminf(minage, 9999.f), 90.f)) / log1pf(90.f);
}

// ---------------- node classifier ------------------------------------------------------
__global__ __launch_bounds__(256) void k_node_cls(
    const float* __restrict__ ne, const float* __restrict__ feat8,
    const float* __restrict__ w1t /*[64][72]*/, const float* __restrict__ b1,
    const float* __restrict__ gamma, const float* __restrict__ beta,
    const float* __restrict__ mean, const float* __restrict__ var,
    const float* __restrict__ w2, const float* __restrict__ b2,
    float* __restrict__ out) {
    int n = blockIdx.x * blockDim.x + threadIdx.x;
    if (n >= N_NODES) return;
    float in[72];
    const float4* nr = (const float4*)(ne + (long)n * 64);
#pragma unroll
    for (int i = 0; i < 16; i++) {
        float4 v = nr[i];
        in[4 * i] = v.x; in[4 * i + 1] = v.y; in[4 * i + 2] = v.z; in[4 * i + 3] = v.w;
    }
    const float4* fr = (const float4*)(feat8 + (long)n * 8);
    float4 f0 = fr[0], f1 = fr[1];
    in[64] = f0.x; in[65] = f0.y; in[66] = f0.z; in[67] = f0.w;
    in[68] = f1.x; in[69] = f1.y; in[70] = f1.z; in[71] = f1.w;
    float logit = b2[0];
    for (int j = 0; j < 64; j++) {
        float h = b1[j];
        const float* wr = w1t + j * 72;
#pragma unroll
        for (int k = 0; k < 72; k++) h = fmaf(in[k], wr[k], h);
        h = (h - mean[j]) * rsqrtf(var[j] + 1e-5f) * gamma[j] + beta[j];
        h = fmaxf(h, 0.f);
        logit = fmaf(h, w2[j], logit);
    }
    out[n] = logit;
}

extern "C" void kernel_launch(void* const* d_in, const int* in_sizes, int n_in,
                              void* d_out, int out_size, void* d_ws, size_t ws_size,
                              hipStream_t stream) {
    const float* x = (const float*)d_in[0];
    const int* eidx = (const int*)d_in[1];
    const int* src = eidx;
    const int* dst = eidx + N_EDGES;
    const float* la = (const float*)d_in[2];
    const float* tse = (const float*)d_in[3];
    const int* bp = (const int*)d_in[4];
    const int* tt = (const int*)d_in[5];
    const float* cr = (const float*)d_in[6];
    const float* tsp = (const float*)d_in[7];
    const float* tg = (const float*)d_in[8];
    const float* r7 = (const float*)d_in[9];
    const float* r30 = (const float*)d_in[10];
    const int* uts = (const int*)d_in[11];
    const float* tx_emb = (const float*)d_in[12];
    const float* bank_emb = (const float*)d_in[13];
    const float* ee_w1 = (const float*)d_in[14];
    const float* ee_b1 = (const float*)d_in[15];
    const float* ee_w2 = (const float*)d_in[16];
    const float* ee_b2 = (const float*)d_in[17];
    const float* msg1_w = (const float*)d_in[18];
    const float* msg1_b = (const float*)d_in[19];
    const float* upd1_w = (const float*)d_in[20];
    const float* upd1_b = (const float*)d_in[21];
    const float* msg2_w = (const float*)d_in[22];
    const float* msg2_b = (const float*)d_in[23];
    const float* upd2_w = (const float*)d_in[24];
    const float* upd2_b = (const float*)d_in[25];
    const float* ec_w1 = (const float*)d_in[26];
    const float* ec_b1 = (const float*)d_in[27];
    const float* ec_w2 = (const float*)d_in[28];
    const float* ec_b2 = (const float*)d_in[29];
    const float* nc_w1 = (const float*)d_in[30];
    const float* nc_b1 = (const float*)d_in[31];
    const float* bn_g = (const float*)d_in[32];
    const float* bn_b = (const float*)d_in[33];
    const float* bn_m = (const float*)d_in[34];
    const float* bn_v = (const float*)d_in[35];
    const float* nc_w2 = (const float*)d_in[36];
    const float* nc_b2 = (const float*)d_in[37];

    float* out_node = (float*)d_out;              // [N_NODES]
    float* out_edge = (float*)d_out + N_NODES;    // [N_EDGES]

    // workspace layout (floats)
    float* ws0 = (float*)d_ws;
    float* eap = ws0;                            // E*32 packed f16, DST-SLOT order
    float* Pp = eap + (long)N_EDGES * 32;        // N*64 packed (einfo alias)
    float* s = Pp + (long)N_NODES * 64;          // N*128 fp32
    float* h1 = s + (long)N_NODES * 128;         // N*128 fp32
    float* ne = h1 + (long)N_NODES * 128;        // N*64 fp32
    float* nSDp = ne + (long)N_NODES * 64;       // N*64 packed (src 32 ++ dst 32)
    float* feat8 = nSDp + (long)N_NODES * 64;    // N*8
    float* Ctp = feat8 + (long)N_NODES * 8;      // 64*32
    float* ncw1t = Ctp + 64 * 32;                // 64*72
    int* tsmax = (int*)(ncw1t + 64 * 72);        // 1
    int* degi = tsmax + 1;                       // N  (dst degree)
    int* degs = degi + N_NODES;                  // N  (src degree; reused as cur_s)
    int* row_d = degs + N_NODES;                 // N+1
    int* row_s = row_d + N_NODES + 1;            // N+1
    int* cur_d = row_s + N_NODES + 1;            // N
    int* eid = cur_d + N_NODES;                  // E (dst-sorted)
    int* eid_src = eid + N_EDGES;                // E (src-sorted)
    int* islot = eid_src + N_EDGES;              // E (edge -> dst slot)
    int* partials = islot + N_EDGES;             // 512
    float* W12tp = (float*)(partials + 512);     // 8960 words
    float* Wm1tp = W12tp + 8960;                 // 4608
    float* Wm2tp = Wm1tp + 4608;                 // 4608
    float* Wpre1 = Wm2tp + 4608;                 // 9216
    float* Wupd1 = Wpre1 + 9216;                 // 18432
    float* Wpre2 = Wupd1 + 18432;                // 9216
    float* Wupd2 = Wpre2 + 9216;                 // 9216
    float* Wec = Wupd2 + 9216;                   // 4608
    float4* einfo = (float4*)Pp;                 // aliases Pp (dead after 2nd msg_seg)

    const int EB = (N_EDGES + 255) / 256;
    const int NB = (N_NODES + 255) / 256;        // 196
    const int NB2 = (N_NODES + 63) / 64;         // 782
    const int MB = (N_EDGES + 63) / 64;          // 7813
    const int EEB = (N_EDGES + 64 * EE_TILES - 1) / (64 * EE_TILES);  // 1954

    // ---- init ----
    hipMemsetAsync(tsmax, 0, (size_t)(1 + 2 * N_NODES) * 4, stream);  // tsmax+degi+degs
    hipMemsetAsync(s, 0, (size_t)N_NODES * 128 * 4, stream);

    // ---- dual-CSR build (cur_s aliases degs; degs dead after scan) ----
    k_deg_count<<<EB, 256, 0, stream>>>(eidx, degi, degs);
    k_block_sums2<<<dim3(NB, 2), 256, 0, stream>>>(degi, degs, partials, N_NODES);
    k_scan_partials2<<<2, 256, 0, stream>>>(partials, NB);
    k_scan_final2<<<dim3(NB, 2), 256, 0, stream>>>(degi, degs, partials,
                                                   row_d, row_s, cur_d, degs, N_NODES);
    k_fill_slots<<<EB, 256, 0, stream>>>(eidx, cur_d, degs, eid, eid_src, islot);

    // ---- weight prep (all LDS-ready f16 images) ----
    k_prep_weights<<<295, 256, 0, stream>>>(ec_w1 + 128 * 64, Ctp, nc_w1, ncw1t,
                                            ee_w1, ee_w2, W12tp,
                                            msg1_w + 128 * 128, Wm1tp,
                                            msg2_w + 128 * 128, Wm2tp,
                                            msg1_w, Wpre1, upd1_w, Wupd1,
                                            msg2_w, Wpre2, upd2_w, Wupd2,
                                            ec_w1, Wec);

    // ---- edge encoder (MFMA; writes ea in dst-slot order) ----
    k_edge_enc_mfma<<<EEB, 256, 0, stream>>>(la, tse, bp, tt, cr, tsp, tg, r7, r30,
                                             tx_emb, bank_emb, W12tp, ee_b1, ee_b2,
                                             islot, eap, N_EDGES);

    // ---- SAGE layer 1 ----
    k_node_gemm_mfma<128, 0, 128, false, false, true><<<NB2, 256, 0, stream>>>(
        x, 128, nullptr, 0, nullptr, Wpre1, nullptr, Pp, 64, N_NODES);
    k_msg_seg_mfma<<<MB, 256, 0, stream>>>(Pp, eap, Wm1tp, msg1_b, src, dst, eid, s, N_EDGES);
    k_node_gemm_mfma<128, 128, 128, true, true, false><<<NB2, 256, 0, stream>>>(
        x, 128, s, 128, degi, Wupd1, upd1_b, h1, 128, N_NODES);

    // ---- SAGE layer 2 ----
    k_node_gemm_mfma<128, 0, 128, false, false, true><<<NB2, 256, 0, stream>>>(
        h1, 128, nullptr, 0, nullptr, Wpre2, nullptr, Pp, 64, N_NODES);
    hipMemsetAsync(s, 0, (size_t)N_NODES * 128 * 4, stream);
    k_msg_seg_mfma<<<MB, 256, 0, stream>>>(Pp, eap, Wm2tp, msg2_b, src, dst, eid, s, N_EDGES);
    k_node_gemm_mfma<128, 128, 64, true, true, false><<<NB2, 256, 0, stream>>>(
        h1, 128, s, 128, degi, Wupd2, upd2_b, ne, 64, N_NODES);
    // Pp dead from here -> einfo alias safe

    // ---- edge classifier prep: ne @ [W_src || W_dst] -> nSDp, one MFMA dispatch ----
    k_node_gemm_mfma<64, 0, 128, false, false, true><<<NB2, 256, 0, stream>>>(
        ne, 64, nullptr, 0, nullptr, Wec, nullptr, nSDp, 64, N_NODES);

    // ---- edge classifier (MFMA + early gathers; ea via islot) ----
    k_tsmax<<<256, 256, 0, stream>>>(uts, tsmax);
    k_edge_cls_mfma<<<MB, 256, 0, stream>>>(nSDp, eap, islot, Ctp, ec_b1, ec_w2, ec_b2,
                                            src, dst, uts, tsmax, out_edge, einfo, N_EDGES);

    // ---- node aggregation (dual CSR) ----
    k_node_agg<<<NB, 256, 0, stream>>>(einfo, row_d, eid, row_s, eid_src, feat8);

    // ---- node classifier ----
    k_node_cls<<<NB, 256, 0, stream>>>(ne, feat8, ncw1t, nc_b1, bn_g, bn_b, bn_m, bn_v,
                                       nc_w2, nc_b2, out_node);
}